// Round 2
// baseline (1845.589 us; speedup 1.0000x reference)
//
#include <hip/hip_runtime.h>
#include <hip/hip_bf16.h>

#define NPTS 2048
#define NB 4
#define KNN 32
#define NIN 33

static __device__ __forceinline__ float b2f(__hip_bfloat16 v) { return __bfloat162float(v); }
#define ISQ 0.99999499996875f /* 1/sqrt(1+1e-5) */

// ---- dtype detect: flag=1 if buffer is bf16, 0 if fp32 ----
__global__ __launch_bounds__(64) void detect_kernel(const unsigned short* __restrict__ x,
                                                    int* __restrict__ flag) {
  int cnt = 0;
  for (int i = threadIdx.x; i < 512; i += 64) {
    unsigned e = (x[i] >> 7) & 0xFFu;
    if (e >= 0xC6u) cnt++;   // |v| >= 2^71: impossible for genuine bf16 activations
  }
#pragma unroll
  for (int off = 32; off > 0; off >>= 1) cnt += __shfl_down(cnt, off);
  if (threadIdx.x == 0) flag[0] = (cnt == 0) ? 1 : 0;
}

// ---- batched convert of all inputs to fp32 pool ----
struct CvtArgs {
  const void* src[NIN];
  int off[NIN + 1];
};

__global__ __launch_bounds__(256) void cvt_all_kernel(CvtArgs a, float* __restrict__ out,
                                                      int total, const int* __restrict__ flag) {
  int t = blockIdx.x * 256 + threadIdx.x;
  if (t >= total) return;
  int s = 0;
  while (t >= a.off[s + 1]) s++;
  int j = t - a.off[s];
  float v;
  if (flag[0]) v = b2f(((const __hip_bfloat16*)a.src[s])[j]);
  else         v = ((const float*)a.src[s])[j];
  out[t] = v;
}

// xx[b,m] = sum_c x[b,c,m]^2
template <int C>
__global__ __launch_bounds__(256) void xx_kernel(const float* __restrict__ x, long bstride,
                                                 float* __restrict__ xx) {
  int t = blockIdx.x * 256 + threadIdx.x;   // b*NPTS + m
  int b = t / NPTS, m = t % NPTS;
  const float* xb = x + (long)b * bstride + m;
  float s = 0.f;
#pragma unroll
  for (int c = 0; c < C; ++c) { float v = xb[(long)c * NPTS]; s = fmaf(v, v, s); }
  xx[t] = s;
}

// one block per (n, b): compute pd row in LDS, then 32x argmax (tie -> lower index)
template <int C>
__global__ __launch_bounds__(256) void knn_kernel(const float* __restrict__ x, long bstride,
                                                  const float* __restrict__ xx,
                                                  int* __restrict__ idxout) {
  __shared__ float pd[NPTS];
  __shared__ float ctr[C > 0 ? C : 1];
  __shared__ float wv[4];
  __shared__ int   wi[4];
  int n = blockIdx.x, b = blockIdx.y, tid = threadIdx.x;
  const float* xb = x + (long)b * bstride;
  if (tid < C) ctr[tid] = xb[(long)tid * NPTS + n];
  __syncthreads();
  float xxn = xx[b * NPTS + n];
  const float* xxb = xx + b * NPTS;
#pragma unroll
  for (int jb = 0; jb < 2; ++jb) {
    int m0 = tid + jb * 1024;
    float d0 = 0.f, d1 = 0.f, d2 = 0.f, d3 = 0.f;
    const float* xp = xb + m0;
#pragma unroll 4
    for (int c = 0; c < C; ++c) {
      float cv = ctr[c];
      const float* row = xp + (long)c * NPTS;
      d0 = fmaf(cv, row[0],   d0);
      d1 = fmaf(cv, row[256], d1);
      d2 = fmaf(cv, row[512], d2);
      d3 = fmaf(cv, row[768], d3);
    }
    pd[m0]       = (-xxn - (-2.f * d0)) - xxb[m0];
    pd[m0 + 256] = (-xxn - (-2.f * d1)) - xxb[m0 + 256];
    pd[m0 + 512] = (-xxn - (-2.f * d2)) - xxb[m0 + 512];
    pd[m0 + 768] = (-xxn - (-2.f * d3)) - xxb[m0 + 768];
  }
  __syncthreads();
  int lane = tid & 63, wave = tid >> 6;
  int* orow = idxout + ((b * NPTS) + n) * KNN;
  for (int k = 0; k < KNN; ++k) {
    float bv = -INFINITY; int bi = NPTS;
#pragma unroll
    for (int j = 0; j < 8; ++j) {
      int m = tid + j * 256;          // ascending m per thread: strict > keeps lowest m
      float v = pd[m];
      if (v > bv) { bv = v; bi = m; }
    }
#pragma unroll
    for (int off = 32; off > 0; off >>= 1) {
      float ov = __shfl_down(bv, off);
      int   oi = __shfl_down(bi, off);
      if (ov > bv || (ov == bv && oi < bi)) { bv = ov; bi = oi; }
    }
    if (lane == 0) { wv[wave] = bv; wi[wave] = bi; }
    __syncthreads();
    if (tid == 0) {
      float fv = wv[0]; int fi = wi[0];
#pragma unroll
      for (int w = 1; w < 4; ++w)
        if (wv[w] > fv || (wv[w] == fv && wi[w] < fi)) { fv = wv[w]; fi = wi[w]; }
      orow[k] = fi;
      pd[fi] = -INFINITY;
    }
    __syncthreads();
  }
}

// y[b,o,m] = sum_c W[o,c] x[b,c,m];  z = sum_c (W[o,C+c]-W[o,c]) x[b,c,m]
template <int C>
__global__ __launch_bounds__(256) void yz_kernel(const float* __restrict__ x, long bstride,
                                                 const float* __restrict__ W, int O,
                                                 float* __restrict__ y, float* __restrict__ z) {
  __shared__ __align__(16) float wly[C * 4];
  __shared__ __align__(16) float wlp[C * 4];
  int b = blockIdx.z, o0 = blockIdx.y * 4;
  int m = blockIdx.x * 256 + threadIdx.x;
  const int twoC = 2 * C;
  for (int lin = threadIdx.x; lin < C * 4; lin += 256) {
    int c = lin >> 2, u = lin & 3;
    wly[lin] = W[(o0 + u) * twoC + c];
    wlp[lin] = W[(o0 + u) * twoC + C + c];
  }
  __syncthreads();
  const float* xb = x + (long)b * bstride + m;
  float y0 = 0, y1 = 0, y2 = 0, y3 = 0, p0 = 0, p1 = 0, p2 = 0, p3 = 0;
#pragma unroll 4
  for (int c = 0; c < C; ++c) {
    float xv = xb[(long)c * NPTS];
    float4 wy = *(const float4*)&wly[c * 4];
    float4 wp = *(const float4*)&wlp[c * 4];
    y0 = fmaf(wy.x, xv, y0); y1 = fmaf(wy.y, xv, y1);
    y2 = fmaf(wy.z, xv, y2); y3 = fmaf(wy.w, xv, y3);
    p0 = fmaf(wp.x, xv, p0); p1 = fmaf(wp.y, xv, p1);
    p2 = fmaf(wp.z, xv, p2); p3 = fmaf(wp.w, xv, p3);
  }
  long base = (long)b * O * NPTS + m;
  y[base + (long)(o0 + 0) * NPTS] = y0;
  y[base + (long)(o0 + 1) * NPTS] = y1;
  y[base + (long)(o0 + 2) * NPTS] = y2;
  y[base + (long)(o0 + 3) * NPTS] = y3;
  z[base + (long)(o0 + 0) * NPTS] = p0 - y0;
  z[base + (long)(o0 + 1) * NPTS] = p1 - y1;
  z[base + (long)(o0 + 2) * NPTS] = p2 - y2;
  z[base + (long)(o0 + 3) * NPTS] = p3 - y3;
}

// out[b,o,n] = max_k leaky(sc[o]*(y[b,o,idx[b,n,k]] + z[b,o,n]) + bias[o])
__global__ __launch_bounds__(256) void gmax_kernel(const float* __restrict__ y,
                                                   const float* __restrict__ z,
                                                   const int* __restrict__ idx,
                                                   const float* __restrict__ g,
                                                   const float* __restrict__ bb,
                                                   int O, float* __restrict__ out, long obstride) {
  int t = blockIdx.x * 256 + threadIdx.x;   // ((b*O)+o)*NPTS + n
  int n = t % NPTS, bo = t / NPTS;
  int o = bo % O, b = bo / O;
  const float* yrow = y + (long)bo * NPTS;
  float zv = z[(long)bo * NPTS + n];
  float sc = g[o] * ISQ;
  float bi = bb[o];
  const int* ip = idx + ((b * NPTS) + n) * KNN;
  float acc = -INFINITY;
#pragma unroll 8
  for (int k = 0; k < KNN; ++k) {
    int j = ip[k];
    float v = fmaf(sc, yrow[j] + zv, bi);
    v = v >= 0.f ? v : 0.2f * v;
    acc = fmaxf(acc, v);
  }
  out[(long)b * obstride + (long)o * NPTS + n] = acc;
}

// fused W5 GEMM + BN + leaky + partial max over 64-wide n tiles
__global__ __launch_bounds__(256) void gemm5_kernel(const float* __restrict__ cat,
                                                    const float* __restrict__ W5,
                                                    const float* __restrict__ g5,
                                                    const float* __restrict__ b5,
                                                    float* __restrict__ pmax) {
  __shared__ __align__(16) float Al[64][17];
  __shared__ __align__(16) float Bl[16][64];
  __shared__ __align__(16) float red[16][4][16];
  int b = blockIdx.z, po0 = blockIdx.y * 64, n0 = blockIdx.x * 64;
  int tid = threadIdx.x, tx = tid & 15, ty = tid >> 4;
  float acc[4][4] = {};
  const float* catb = cat + (long)b * 512 * NPTS;
  for (int k0 = 0; k0 < 512; k0 += 16) {
#pragma unroll
    for (int i = 0; i < 4; ++i) {
      int lin = tid + i * 256;
      Al[lin >> 4][lin & 15] = W5[(long)(po0 + (lin >> 4)) * 512 + k0 + (lin & 15)];
    }
#pragma unroll
    for (int i = 0; i < 4; ++i) {
      int lin = tid + i * 256;
      Bl[lin >> 6][lin & 63] = catb[(long)(k0 + (lin >> 6)) * NPTS + n0 + (lin & 63)];
    }
    __syncthreads();
#pragma unroll
    for (int kc = 0; kc < 16; ++kc) {
      float a0 = Al[ty * 4 + 0][kc], a1 = Al[ty * 4 + 1][kc];
      float a2 = Al[ty * 4 + 2][kc], a3 = Al[ty * 4 + 3][kc];
      float4 bv = *(const float4*)&Bl[kc][tx * 4];
      acc[0][0] = fmaf(a0, bv.x, acc[0][0]); acc[0][1] = fmaf(a0, bv.y, acc[0][1]);
      acc[0][2] = fmaf(a0, bv.z, acc[0][2]); acc[0][3] = fmaf(a0, bv.w, acc[0][3]);
      acc[1][0] = fmaf(a1, bv.x, acc[1][0]); acc[1][1] = fmaf(a1, bv.y, acc[1][1]);
      acc[1][2] = fmaf(a1, bv.z, acc[1][2]); acc[1][3] = fmaf(a1, bv.w, acc[1][3]);
      acc[2][0] = fmaf(a2, bv.x, acc[2][0]); acc[2][1] = fmaf(a2, bv.y, acc[2][1]);
      acc[2][2] = fmaf(a2, bv.z, acc[2][2]); acc[2][3] = fmaf(a2, bv.w, acc[2][3]);
      acc[3][0] = fmaf(a3, bv.x, acc[3][0]); acc[3][1] = fmaf(a3, bv.y, acc[3][1]);
      acc[3][2] = fmaf(a3, bv.z, acc[3][2]); acc[3][3] = fmaf(a3, bv.w, acc[3][3]);
    }
    __syncthreads();
  }
#pragma unroll
  for (int i = 0; i < 4; ++i) {
    int po = po0 + ty * 4 + i;
    float sc = g5[po] * ISQ;
    float bi = b5[po];
    float mx = -INFINITY;
#pragma unroll
    for (int j = 0; j < 4; ++j) {
      float v = fmaf(sc, acc[i][j], bi);
      v = v >= 0.f ? v : 0.2f * v;
      mx = fmaxf(mx, v);
    }
    red[ty][i][tx] = mx;
  }
  __syncthreads();
  if (tid < 64) {
    float mx = red[tid >> 2][tid & 3][0];
#pragma unroll
    for (int t2 = 1; t2 < 16; ++t2) mx = fmaxf(mx, red[tid >> 2][tid & 3][t2]);
    pmax[(long)(b * 1024 + po0 + tid) * 32 + blockIdx.x] = mx;
  }
}

__global__ __launch_bounds__(256) void reduce5_kernel(const float* __restrict__ pmax,
                                                      float* __restrict__ v) {
  int t = blockIdx.x * 256 + threadIdx.x;   // b*1024 + po  (4096)
  float mx = -INFINITY;
#pragma unroll
  for (int j = 0; j < 32; ++j) mx = fmaxf(mx, pmax[(long)t * 32 + j]);
  int b = t >> 10, po = t & 1023;
  v[b * 1152 + po] = mx;
}

__global__ __launch_bounds__(128) void lfnf_kernel(const float* __restrict__ l,
                                                   const float* __restrict__ nn,
                                                   const float* __restrict__ W6,
                                                   const float* __restrict__ g6,
                                                   const float* __restrict__ b6,
                                                   const float* __restrict__ W7,
                                                   const float* __restrict__ g7,
                                                   const float* __restrict__ b7,
                                                   float* __restrict__ v) {
  int b = blockIdx.x, t = threadIdx.x;
  if (t < 64) {
    float s = 0.f;
#pragma unroll
    for (int c = 0; c < 5; ++c) s = fmaf(W6[t * 5 + c], l[b * 5 + c], s);
    float val = fmaf(g6[t] * ISQ, s, b6[t]);
    v[b * 1152 + 1024 + t] = val >= 0.f ? val : 0.2f * val;
  } else {
    int o = t - 64;
    float s = 0.f;
#pragma unroll
    for (int c = 0; c < 7; ++c) s = fmaf(W7[o * 7 + c], nn[b * 7 + c], s);
    float val = fmaf(g7[o] * ISQ, s, b7[o]);
    v[b * 1152 + 1088 + o] = val >= 0.f ? val : 0.2f * val;
  }
}

__global__ __launch_bounds__(256) void head1_kernel(const float* __restrict__ v,
                                                    const float* __restrict__ L1,
                                                    const float* __restrict__ g8,
                                                    const float* __restrict__ b8,
                                                    float* __restrict__ v1) {
  int t = blockIdx.x * 256 + threadIdx.x;   // b*512 + o  (2048)
  int b = t >> 9, o = t & 511;
  const float* vb = v + b * 1152;
  const float* wr = L1 + (long)o * 1152;
  float s = 0.f;
#pragma unroll 4
  for (int c = 0; c < 1152; ++c) s = fmaf(wr[c], vb[c], s);
  float val = fmaf(g8[o] * ISQ, s, b8[o]);
  v1[t] = fmaxf(val, 0.f);
}

__global__ __launch_bounds__(256) void head2_kernel(const float* __restrict__ v1,
                                                    const float* __restrict__ L2,
                                                    const float* __restrict__ L2b,
                                                    const float* __restrict__ g9,
                                                    const float* __restrict__ b9,
                                                    float* __restrict__ v2) {
  int t = blockIdx.x * 256 + threadIdx.x;   // b*256 + o  (1024)
  int b = t >> 8, o = t & 255;
  const float* vb = v1 + b * 512;
  const float* wr = L2 + (long)o * 512;
  float s = 0.f;
#pragma unroll 4
  for (int c = 0; c < 512; ++c) s = fmaf(wr[c], vb[c], s);
  s += L2b[o];
  float val = fmaf(g9[o] * ISQ, s, b9[o]);
  v2[t] = fmaxf(val, 0.f);
}

__global__ __launch_bounds__(128) void head3_kernel(const float* __restrict__ v2,
                                                    const float* __restrict__ L3,
                                                    const float* __restrict__ L3b,
                                                    void* __restrict__ out,
                                                    const int* __restrict__ flag) {
  int t = threadIdx.x;   // b*28 + o  (112)
  if (t >= 112) return;
  int b = t / 28, o = t % 28;
  const float* vb = v2 + b * 256;
  const float* wr = L3 + o * 256;
  float s = 0.f;
#pragma unroll 4
  for (int c = 0; c < 256; ++c) s = fmaf(wr[c], vb[c], s);
  s += L3b[o];
  if (flag[0]) ((__hip_bfloat16*)out)[t] = __float2bfloat16(s);
  else         ((float*)out)[t] = s;
}

extern "C" void kernel_launch(void* const* d_in, const int* in_sizes, int n_in,
                              void* d_out, int out_size, void* d_ws, size_t ws_size,
                              hipStream_t stream) {
  // offsets of each input in the fp32 pool
  CvtArgs ca;
  int off[NIN + 1];
  off[0] = 0;
  for (int i = 0; i < NIN; ++i) {
    ca.src[i] = d_in[i];
    off[i + 1] = off[i] + in_sizes[i];
    ca.off[i] = off[i];
  }
  ca.off[NIN] = off[NIN];
  const int total = off[NIN];

  int* flag = (int*)d_ws;
  float* fin = (float*)((char*)d_ws + 64);
  // converted-input pointers
  const float* xf  = fin + off[0];
  const float* lf  = fin + off[1];
  const float* nf  = fin + off[2];
  const float* W1f = fin + off[3];  const float* g1f = fin + off[4];  const float* b1f = fin + off[5];
  const float* W2f = fin + off[6];  const float* g2f = fin + off[7];  const float* b2f_ = fin + off[8];
  const float* W3f = fin + off[9];  const float* g3f = fin + off[10]; const float* b3f = fin + off[11];
  const float* W4f = fin + off[12]; const float* g4f = fin + off[13]; const float* b4f = fin + off[14];
  const float* W5f = fin + off[15]; const float* g5f = fin + off[16]; const float* b5f = fin + off[17];
  const float* W6f = fin + off[18]; const float* g6f = fin + off[19]; const float* b6f = fin + off[20];
  const float* W7f = fin + off[21]; const float* g7f = fin + off[22]; const float* b7f = fin + off[23];
  const float* L1f = fin + off[24]; const float* g8f = fin + off[25]; const float* b8f = fin + off[26];
  const float* L2f = fin + off[27]; const float* L2bf = fin + off[28];
  const float* g9f = fin + off[29]; const float* b9f = fin + off[30];
  const float* L3f = fin + off[31]; const float* L3bf = fin + off[32];

  // scratch carve after the pool (16-float aligned)
  float* p = fin + ((total + 15) & ~15);
  float* cat  = p;                            // 4*512*2048
  float* yb   = cat + 4 * 512 * NPTS;         // 4*256*2048
  float* zb   = yb + 4 * 256 * NPTS;          // 4*256*2048
  float* xxb  = zb + 4 * 256 * NPTS;          // 4*2048
  int*   idxb = (int*)(xxb + 4 * NPTS);       // 4*2048*32
  float* pmax = (float*)(idxb + 4 * NPTS * KNN); // 4*1024*32
  float* vb   = pmax + 4 * 1024 * 32;         // 4*1152
  float* v1b  = vb + 4 * 1152;                // 4*512
  float* v2b  = v1b + 4 * 512;                // 4*256

  const long bst1 = 3L * NPTS;
  const long bstc = 512L * NPTS;

  detect_kernel<<<1, 64, 0, stream>>>((const unsigned short*)d_in[0], flag);
  cvt_all_kernel<<<(total + 255) / 256, 256, 0, stream>>>(ca, fin, total, flag);

  // ---- layer 1: C=3, O=64, in=xf, out=cat[:,0:64,:]
  xx_kernel<3><<<32, 256, 0, stream>>>(xf, bst1, xxb);
  knn_kernel<3><<<dim3(NPTS, NB), 256, 0, stream>>>(xf, bst1, xxb, idxb);
  yz_kernel<3><<<dim3(8, 16, NB), 256, 0, stream>>>(xf, bst1, W1f, 64, yb, zb);
  gmax_kernel<<<(NB * 64 * NPTS) / 256, 256, 0, stream>>>(yb, zb, idxb, g1f, b1f, 64, cat, bstc);

  // ---- layer 2: C=64, O=64
  xx_kernel<64><<<32, 256, 0, stream>>>(cat, bstc, xxb);
  knn_kernel<64><<<dim3(NPTS, NB), 256, 0, stream>>>(cat, bstc, xxb, idxb);
  yz_kernel<64><<<dim3(8, 16, NB), 256, 0, stream>>>(cat, bstc, W2f, 64, yb, zb);
  gmax_kernel<<<(NB * 64 * NPTS) / 256, 256, 0, stream>>>(yb, zb, idxb, g2f, b2f_, 64, cat + 64L * NPTS, bstc);

  // ---- layer 3: C=64, O=128
  xx_kernel<64><<<32, 256, 0, stream>>>(cat + 64L * NPTS, bstc, xxb);
  knn_kernel<64><<<dim3(NPTS, NB), 256, 0, stream>>>(cat + 64L * NPTS, bstc, xxb, idxb);
  yz_kernel<64><<<dim3(8, 32, NB), 256, 0, stream>>>(cat + 64L * NPTS, bstc, W3f, 128, yb, zb);
  gmax_kernel<<<(NB * 128 * NPTS) / 256, 256, 0, stream>>>(yb, zb, idxb, g3f, b3f, 128, cat + 128L * NPTS, bstc);

  // ---- layer 4: C=128, O=256
  xx_kernel<128><<<32, 256, 0, stream>>>(cat + 128L * NPTS, bstc, xxb);
  knn_kernel<128><<<dim3(NPTS, NB), 256, 0, stream>>>(cat + 128L * NPTS, bstc, xxb, idxb);
  yz_kernel<128><<<dim3(8, 64, NB), 256, 0, stream>>>(cat + 128L * NPTS, bstc, W4f, 256, yb, zb);
  gmax_kernel<<<(NB * 256 * NPTS) / 256, 256, 0, stream>>>(yb, zb, idxb, g4f, b4f, 256, cat + 256L * NPTS, bstc);

  // ---- conv5 (1024x512) + BN + leaky + global max over N
  gemm5_kernel<<<dim3(32, 16, NB), 256, 0, stream>>>(cat, W5f, g5f, b5f, pmax);
  reduce5_kernel<<<16, 256, 0, stream>>>(pmax, vb);

  // ---- lf / nf
  lfnf_kernel<<<NB, 128, 0, stream>>>(lf, nf, W6f, g6f, b6f, W7f, g7f, b7f, vb);

  // ---- head
  head1_kernel<<<8, 256, 0, stream>>>(vb, L1f, g8f, b8f, v1b);
  head2_kernel<<<4, 256, 0, stream>>>(v1b, L2f, L2bf, g9f, b9f, v2b);
  head3_kernel<<<1, 128, 0, stream>>>(v2b, L3f, L3bf, d_out, flag);
}

// Round 3
// 1369.920 us; speedup vs baseline: 1.3472x; 1.3472x over previous
//
#include <hip/hip_runtime.h>
#include <hip/hip_bf16.h>

#define NPTS 2048
#define NB 4
#define KNN 32
#define NIN 33

static __device__ __forceinline__ float b2f(__hip_bfloat16 v) { return __bfloat162float(v); }
#define ISQ 0.99999499996875f /* 1/sqrt(1+1e-5) */

// monotone order-preserving key for fp32 (no NaNs): a<b  <=>  ordkey(a)<ordkey(b)
static __device__ __forceinline__ unsigned ordkey(float f) {
  unsigned u = __float_as_uint(f);
  return u ^ (unsigned)(((int)u >> 31) | 0x80000000);
}

// ---- dtype detect: flag=1 if buffer is bf16, 0 if fp32 ----
__global__ __launch_bounds__(64) void detect_kernel(const unsigned short* __restrict__ x,
                                                    int* __restrict__ flag) {
  int cnt = 0;
  for (int i = threadIdx.x; i < 512; i += 64) {
    unsigned e = (x[i] >> 7) & 0xFFu;
    if (e >= 0xC6u) cnt++;
  }
#pragma unroll
  for (int off = 32; off > 0; off >>= 1) cnt += __shfl_down(cnt, off);
  if (threadIdx.x == 0) flag[0] = (cnt == 0) ? 1 : 0;
}

struct CvtArgs {
  const void* src[NIN];
  int off[NIN + 1];
};

__global__ __launch_bounds__(256) void cvt_all_kernel(CvtArgs a, float* __restrict__ out,
                                                      int total, const int* __restrict__ flag) {
  int t = blockIdx.x * 256 + threadIdx.x;
  if (t >= total) return;
  int s = 0;
  while (t >= a.off[s + 1]) s++;
  int j = t - a.off[s];
  float v;
  if (flag[0]) v = b2f(((const __hip_bfloat16*)a.src[s])[j]);
  else         v = ((const float*)a.src[s])[j];
  out[t] = v;
}

// xx[b,m] = sum_c x[b,c,m]^2
template <int C>
__global__ __launch_bounds__(256) void xx_kernel(const float* __restrict__ x, long bstride,
                                                 float* __restrict__ xx) {
  int t = blockIdx.x * 256 + threadIdx.x;
  int b = t / NPTS, m = t % NPTS;
  const float* xb = x + (long)b * bstride + m;
  float s = 0.f;
#pragma unroll
  for (int c = 0; c < C; ++c) { float v = xb[(long)c * NPTS]; s = fmaf(v, v, s); }
  xx[t] = s;
}

// pd-GEMM: keys[b][n][m] = ordkey( (-xx[n] - (-2*dot(x_n,x_m))) - xx[m] )
// 64x64 tile per block, 4x4 micro; x,xx pre-offset to batch group; blockIdx.z = local b
template <int C>
__global__ __launch_bounds__(256) void pdgemm_kernel(const float* __restrict__ x, long bstride,
                                                     const float* __restrict__ xx,
                                                     unsigned* __restrict__ keys) {
  constexpr int KT = (C < 16) ? C : 16;
  __shared__ __align__(16) float At[KT][64];
  __shared__ __align__(16) float Bt[KT][64];
  int n0 = blockIdx.y * 64, m0 = blockIdx.x * 64;
  int tid = threadIdx.x, tx = tid & 15, ty = tid >> 4;
  const float* xb = x + (long)blockIdx.z * bstride;
  float acc[4][4] = {};
  for (int k0 = 0; k0 < C; k0 += KT) {
    for (int lin = tid; lin < KT * 64; lin += 256) {
      int r = lin >> 6, col = lin & 63;
      At[r][col] = xb[(long)(k0 + r) * NPTS + n0 + col];
      Bt[r][col] = xb[(long)(k0 + r) * NPTS + m0 + col];
    }
    __syncthreads();
#pragma unroll
    for (int kc = 0; kc < KT; ++kc) {
      float4 av = *(const float4*)&At[kc][ty * 4];
      float4 bv = *(const float4*)&Bt[kc][tx * 4];
      acc[0][0] = fmaf(av.x, bv.x, acc[0][0]); acc[0][1] = fmaf(av.x, bv.y, acc[0][1]);
      acc[0][2] = fmaf(av.x, bv.z, acc[0][2]); acc[0][3] = fmaf(av.x, bv.w, acc[0][3]);
      acc[1][0] = fmaf(av.y, bv.x, acc[1][0]); acc[1][1] = fmaf(av.y, bv.y, acc[1][1]);
      acc[1][2] = fmaf(av.y, bv.z, acc[1][2]); acc[1][3] = fmaf(av.y, bv.w, acc[1][3]);
      acc[2][0] = fmaf(av.z, bv.x, acc[2][0]); acc[2][1] = fmaf(av.z, bv.y, acc[2][1]);
      acc[2][2] = fmaf(av.z, bv.z, acc[2][2]); acc[2][3] = fmaf(av.z, bv.w, acc[2][3]);
      acc[3][0] = fmaf(av.w, bv.x, acc[3][0]); acc[3][1] = fmaf(av.w, bv.y, acc[3][1]);
      acc[3][2] = fmaf(av.w, bv.z, acc[3][2]); acc[3][3] = fmaf(av.w, bv.w, acc[3][3]);
    }
    __syncthreads();
  }
  const float* xxq = xx + (long)blockIdx.z * NPTS;
  float4 xxm = *(const float4*)&xxq[m0 + tx * 4];
  unsigned* kb = keys + ((long)blockIdx.z << 22);
#pragma unroll
  for (int i = 0; i < 4; ++i) {
    float xxn = xxq[n0 + ty * 4 + i];
    uint4 o;
    o.x = ordkey((-xxn - (-2.f * acc[i][0])) - xxm.x);
    o.y = ordkey((-xxn - (-2.f * acc[i][1])) - xxm.y);
    o.z = ordkey((-xxn - (-2.f * acc[i][2])) - xxm.z);
    o.w = ordkey((-xxn - (-2.f * acc[i][3])) - xxm.w);
    *(uint4*)&kb[(long)(n0 + ty * 4 + i) * NPTS + m0 + tx * 4] = o;
  }
}

// top-32 select: one wave per query row. Keys u64 = (ord(pd)<<32) | ~m  (distinct;
// max = largest pd, ties -> lowest m). Lazy per-lane top-2; 6-step xor-butterfly per round.
__global__ __launch_bounds__(256) void select_kernel(const unsigned* __restrict__ keys,
                                                     int* __restrict__ idxout) {
  int wave = threadIdx.x >> 6, lane = threadIdx.x & 63;
  int q = blockIdx.x * 4 + wave;
  int bloc = q >> 11, n = q & 2047;
  const uint4* rp = (const uint4*)(keys + ((long)((bloc << 11) | n) << 11));
  unsigned long long K[32];
#pragma unroll
  for (int t = 0; t < 8; ++t) {
    uint4 kk = rp[t * 64 + lane];
    unsigned mb = t * 256 + lane * 4;
    K[4 * t + 0] = ((unsigned long long)kk.x << 32) | (unsigned)~(mb + 0);
    K[4 * t + 1] = ((unsigned long long)kk.y << 32) | (unsigned)~(mb + 1);
    K[4 * t + 2] = ((unsigned long long)kk.z << 32) | (unsigned)~(mb + 2);
    K[4 * t + 3] = ((unsigned long long)kk.w << 32) | (unsigned)~(mb + 3);
  }
  unsigned long long a1 = 0, a2 = 0, keep = 0;
#pragma unroll
  for (int s = 0; s < 32; ++s) {
    unsigned long long k = K[s];
    if (k > a1) { a2 = a1; a1 = k; }
    else if (k > a2) a2 = k;
  }
  for (int r = 0; r < KNN; ++r) {
    unsigned long long W = a1;
#pragma unroll
    for (int xm = 32; xm >= 1; xm >>= 1) {
      unsigned long long o = __shfl_xor(W, xm);
      if (o > W) W = o;
    }
    if (lane == r) keep = W;
    if (a1 == W) {           // unique owner (keys distinct)
      if (a2) { a1 = a2; a2 = 0; }
      else {
        unsigned long long mx = 0;
#pragma unroll
        for (int s = 0; s < 32; ++s) {
          unsigned long long c = (K[s] < W) ? K[s] : 0ULL;
          mx = c > mx ? c : mx;
        }
        a1 = mx;
      }
    }
  }
  if (lane < KNN)
    idxout[((bloc << 11) | n) * KNN + lane] = (int)(~(unsigned)(keep & 0xFFFFFFFFull));
}

// y[b,o,m] = sum_c W[o,c] x[b,c,m];  z = sum_c (W[o,C+c]-W[o,c]) x[b,c,m]
template <int C>
__global__ __launch_bounds__(256) void yz_kernel(const float* __restrict__ x, long bstride,
                                                 const float* __restrict__ W, int O,
                                                 float* __restrict__ y, float* __restrict__ z) {
  __shared__ __align__(16) float wly[C * 4];
  __shared__ __align__(16) float wlp[C * 4];
  int b = blockIdx.z, o0 = blockIdx.y * 4;
  int m = blockIdx.x * 256 + threadIdx.x;
  const int twoC = 2 * C;
  for (int lin = threadIdx.x; lin < C * 4; lin += 256) {
    int c = lin >> 2, u = lin & 3;
    wly[lin] = W[(o0 + u) * twoC + c];
    wlp[lin] = W[(o0 + u) * twoC + C + c];
  }
  __syncthreads();
  const float* xb = x + (long)b * bstride + m;
  float y0 = 0, y1 = 0, y2 = 0, y3 = 0, p0 = 0, p1 = 0, p2 = 0, p3 = 0;
#pragma unroll 4
  for (int c = 0; c < C; ++c) {
    float xv = xb[(long)c * NPTS];
    float4 wy = *(const float4*)&wly[c * 4];
    float4 wp = *(const float4*)&wlp[c * 4];
    y0 = fmaf(wy.x, xv, y0); y1 = fmaf(wy.y, xv, y1);
    y2 = fmaf(wy.z, xv, y2); y3 = fmaf(wy.w, xv, y3);
    p0 = fmaf(wp.x, xv, p0); p1 = fmaf(wp.y, xv, p1);
    p2 = fmaf(wp.z, xv, p2); p3 = fmaf(wp.w, xv, p3);
  }
  long base = (long)b * O * NPTS + m;
  y[base + (long)(o0 + 0) * NPTS] = y0;
  y[base + (long)(o0 + 1) * NPTS] = y1;
  y[base + (long)(o0 + 2) * NPTS] = y2;
  y[base + (long)(o0 + 3) * NPTS] = y3;
  z[base + (long)(o0 + 0) * NPTS] = p0 - y0;
  z[base + (long)(o0 + 1) * NPTS] = p1 - y1;
  z[base + (long)(o0 + 2) * NPTS] = p2 - y2;
  z[base + (long)(o0 + 3) * NPTS] = p3 - y3;
}

// out[b,o,n] = max_k leaky(sc[o]*(y[b,o,idx[b,n,k]] + z[b,o,n]) + bias[o])
__global__ __launch_bounds__(256) void gmax_kernel(const float* __restrict__ y,
                                                   const float* __restrict__ z,
                                                   const int* __restrict__ idx,
                                                   const float* __restrict__ g,
                                                   const float* __restrict__ bb,
                                                   int O, float* __restrict__ out, long obstride) {
  int t = blockIdx.x * 256 + threadIdx.x;
  int n = t % NPTS, bo = t / NPTS;
  int o = bo % O, b = bo / O;
  const float* yrow = y + (long)bo * NPTS;
  float zv = z[(long)bo * NPTS + n];
  float sc = g[o] * ISQ;
  float bi = bb[o];
  const int* ip = idx + ((b * NPTS) + n) * KNN;
  float acc = -INFINITY;
#pragma unroll 8
  for (int k = 0; k < KNN; ++k) {
    int j = ip[k];
    float v = fmaf(sc, yrow[j] + zv, bi);
    v = v >= 0.f ? v : 0.2f * v;
    acc = fmaxf(acc, v);
  }
  out[(long)b * obstride + (long)o * NPTS + n] = acc;
}

// fused W5 GEMM + BN + leaky + partial max over 64-wide n tiles
__global__ __launch_bounds__(256) void gemm5_kernel(const float* __restrict__ cat,
                                                    const float* __restrict__ W5,
                                                    const float* __restrict__ g5,
                                                    const float* __restrict__ b5,
                                                    float* __restrict__ pmax) {
  __shared__ __align__(16) float Al[64][17];
  __shared__ __align__(16) float Bl[16][64];
  __shared__ __align__(16) float red[16][4][16];
  int b = blockIdx.z, po0 = blockIdx.y * 64, n0 = blockIdx.x * 64;
  int tid = threadIdx.x, tx = tid & 15, ty = tid >> 4;
  float acc[4][4] = {};
  const float* catb = cat + (long)b * 512 * NPTS;
  for (int k0 = 0; k0 < 512; k0 += 16) {
#pragma unroll
    for (int i = 0; i < 4; ++i) {
      int lin = tid + i * 256;
      Al[lin >> 4][lin & 15] = W5[(long)(po0 + (lin >> 4)) * 512 + k0 + (lin & 15)];
    }
#pragma unroll
    for (int i = 0; i < 4; ++i) {
      int lin = tid + i * 256;
      Bl[lin >> 6][lin & 63] = catb[(long)(k0 + (lin >> 6)) * NPTS + n0 + (lin & 63)];
    }
    __syncthreads();
#pragma unroll
    for (int kc = 0; kc < 16; ++kc) {
      float a0 = Al[ty * 4 + 0][kc], a1 = Al[ty * 4 + 1][kc];
      float a2 = Al[ty * 4 + 2][kc], a3 = Al[ty * 4 + 3][kc];
      float4 bv = *(const float4*)&Bl[kc][tx * 4];
      acc[0][0] = fmaf(a0, bv.x, acc[0][0]); acc[0][1] = fmaf(a0, bv.y, acc[0][1]);
      acc[0][2] = fmaf(a0, bv.z, acc[0][2]); acc[0][3] = fmaf(a0, bv.w, acc[0][3]);
      acc[1][0] = fmaf(a1, bv.x, acc[1][0]); acc[1][1] = fmaf(a1, bv.y, acc[1][1]);
      acc[1][2] = fmaf(a1, bv.z, acc[1][2]); acc[1][3] = fmaf(a1, bv.w, acc[1][3]);
      acc[2][0] = fmaf(a2, bv.x, acc[2][0]); acc[2][1] = fmaf(a2, bv.y, acc[2][1]);
      acc[2][2] = fmaf(a2, bv.z, acc[2][2]); acc[2][3] = fmaf(a2, bv.w, acc[2][3]);
      acc[3][0] = fmaf(a3, bv.x, acc[3][0]); acc[3][1] = fmaf(a3, bv.y, acc[3][1]);
      acc[3][2] = fmaf(a3, bv.z, acc[3][2]); acc[3][3] = fmaf(a3, bv.w, acc[3][3]);
    }
    __syncthreads();
  }
#pragma unroll
  for (int i = 0; i < 4; ++i) {
    int po = po0 + ty * 4 + i;
    float sc = g5[po] * ISQ;
    float bi = b5[po];
    float mx = -INFINITY;
#pragma unroll
    for (int j = 0; j < 4; ++j) {
      float v = fmaf(sc, acc[i][j], bi);
      v = v >= 0.f ? v : 0.2f * v;
      mx = fmaxf(mx, v);
    }
    red[ty][i][tx] = mx;
  }
  __syncthreads();
  if (tid < 64) {
    float mx = red[tid >> 2][tid & 3][0];
#pragma unroll
    for (int t2 = 1; t2 < 16; ++t2) mx = fmaxf(mx, red[tid >> 2][tid & 3][t2]);
    pmax[(long)(b * 1024 + po0 + tid) * 32 + blockIdx.x] = mx;
  }
}

__global__ __launch_bounds__(256) void reduce5_kernel(const float* __restrict__ pmax,
                                                      float* __restrict__ v) {
  int t = blockIdx.x * 256 + threadIdx.x;
  float mx = -INFINITY;
#pragma unroll
  for (int j = 0; j < 32; ++j) mx = fmaxf(mx, pmax[(long)t * 32 + j]);
  int b = t >> 10, po = t & 1023;
  v[b * 1152 + po] = mx;
}

__global__ __launch_bounds__(128) void lfnf_kernel(const float* __restrict__ l,
                                                   const float* __restrict__ nn,
                                                   const float* __restrict__ W6,
                                                   const float* __restrict__ g6,
                                                   const float* __restrict__ b6,
                                                   const float* __restrict__ W7,
                                                   const float* __restrict__ g7,
                                                   const float* __restrict__ b7,
                                                   float* __restrict__ v) {
  int b = blockIdx.x, t = threadIdx.x;
  if (t < 64) {
    float s = 0.f;
#pragma unroll
    for (int c = 0; c < 5; ++c) s = fmaf(W6[t * 5 + c], l[b * 5 + c], s);
    float val = fmaf(g6[t] * ISQ, s, b6[t]);
    v[b * 1152 + 1024 + t] = val >= 0.f ? val : 0.2f * val;
  } else {
    int o = t - 64;
    float s = 0.f;
#pragma unroll
    for (int c = 0; c < 7; ++c) s = fmaf(W7[o * 7 + c], nn[b * 7 + c], s);
    float val = fmaf(g7[o] * ISQ, s, b7[o]);
    v[b * 1152 + 1088 + o] = val >= 0.f ? val : 0.2f * val;
  }
}

__global__ __launch_bounds__(256) void head1_kernel(const float* __restrict__ v,
                                                    const float* __restrict__ L1,
                                                    const float* __restrict__ g8,
                                                    const float* __restrict__ b8,
                                                    float* __restrict__ v1) {
  int t = blockIdx.x * 256 + threadIdx.x;
  int b = t >> 9, o = t & 511;
  const float* vb = v + b * 1152;
  const float* wr = L1 + (long)o * 1152;
  float s = 0.f;
#pragma unroll 4
  for (int c = 0; c < 1152; ++c) s = fmaf(wr[c], vb[c], s);
  float val = fmaf(g8[o] * ISQ, s, b8[o]);
  v1[t] = fmaxf(val, 0.f);
}

__global__ __launch_bounds__(256) void head2_kernel(const float* __restrict__ v1,
                                                    const float* __restrict__ L2,
                                                    const float* __restrict__ L2b,
                                                    const float* __restrict__ g9,
                                                    const float* __restrict__ b9,
                                                    float* __restrict__ v2) {
  int t = blockIdx.x * 256 + threadIdx.x;
  int b = t >> 8, o = t & 255;
  const float* vb = v1 + b * 512;
  const float* wr = L2 + (long)o * 512;
  float s = 0.f;
#pragma unroll 4
  for (int c = 0; c < 512; ++c) s = fmaf(wr[c], vb[c], s);
  s += L2b[o];
  float val = fmaf(g9[o] * ISQ, s, b9[o]);
  v2[t] = fmaxf(val, 0.f);
}

__global__ __launch_bounds__(128) void head3_kernel(const float* __restrict__ v2,
                                                    const float* __restrict__ L3,
                                                    const float* __restrict__ L3b,
                                                    void* __restrict__ out,
                                                    const int* __restrict__ flag) {
  int t = threadIdx.x;
  if (t >= 112) return;
  int b = t / 28, o = t % 28;
  const float* vb = v2 + b * 256;
  const float* wr = L3 + o * 256;
  float s = 0.f;
#pragma unroll 4
  for (int c = 0; c < 256; ++c) s = fmaf(wr[c], vb[c], s);
  s += L3b[o];
  if (flag[0]) ((__hip_bfloat16*)out)[t] = __float2bfloat16(s);
  else         ((float*)out)[t] = s;
}

extern "C" void kernel_launch(void* const* d_in, const int* in_sizes, int n_in,
                              void* d_out, int out_size, void* d_ws, size_t ws_size,
                              hipStream_t stream) {
  CvtArgs ca;
  int off[NIN + 1];
  off[0] = 0;
  for (int i = 0; i < NIN; ++i) {
    ca.src[i] = d_in[i];
    off[i + 1] = off[i] + in_sizes[i];
    ca.off[i] = off[i];
  }
  ca.off[NIN] = off[NIN];
  const int total = off[NIN];

  int* flag = (int*)d_ws;
  float* fin = (float*)((char*)d_ws + 64);
  const float* xf  = fin + off[0];
  const float* lf  = fin + off[1];
  const float* nf  = fin + off[2];
  const float* W1f = fin + off[3];  const float* g1f = fin + off[4];  const float* b1f = fin + off[5];
  const float* W2f = fin + off[6];  const float* g2f = fin + off[7];  const float* b2f_ = fin + off[8];
  const float* W3f = fin + off[9];  const float* g3f = fin + off[10]; const float* b3f = fin + off[11];
  const float* W4f = fin + off[12]; const float* g4f = fin + off[13]; const float* b4f = fin + off[14];
  const float* W5f = fin + off[15]; const float* g5f = fin + off[16]; const float* b5f = fin + off[17];
  const float* W6f = fin + off[18]; const float* g6f = fin + off[19]; const float* b6f = fin + off[20];
  const float* W7f = fin + off[21]; const float* g7f = fin + off[22]; const float* b7f = fin + off[23];
  const float* L1f = fin + off[24]; const float* g8f = fin + off[25]; const float* b8f = fin + off[26];
  const float* L2f = fin + off[27]; const float* L2bf = fin + off[28];
  const float* g9f = fin + off[29]; const float* b9f = fin + off[30];
  const float* L3f = fin + off[31]; const float* L3bf = fin + off[32];

  float* p = fin + ((total + 15) & ~15);
  float* cat  = p;                               // 4*512*2048
  float* yb   = cat + 4 * 512 * NPTS;            // 4*256*2048
  float* zb   = yb + 4 * 256 * NPTS;             // 4*256*2048
  float* xxb  = zb + 4 * 256 * NPTS;             // 4*2048
  int*   idxb = (int*)(xxb + 4 * NPTS);          // 4*2048*32
  float* pmax = (float*)(idxb + 4 * NPTS * KNN); // 4*1024*32
  float* vb   = pmax + 4 * 1024 * 32;            // 4*1152
  float* v1b  = vb + 4 * 1152;                   // 4*512
  float* v2b  = v1b + 4 * 512;                   // 4*256
  unsigned* keys_tail = (unsigned*)(v2b + 4 * 256);

  // keys: 4 batches at tail if ws allows, else 1 batch overlaid on yb/zb (dead there)
  size_t need_full = (size_t)((char*)(keys_tail + (size_t)NB * NPTS * NPTS) - (char*)d_ws);
  int bpass = (ws_size >= need_full) ? NB : 1;
  unsigned* keys = (bpass == NB) ? keys_tail : (unsigned*)yb;

  const long bst1 = 3L * NPTS;
  const long bstc = 512L * NPTS;

  detect_kernel<<<1, 64, 0, stream>>>((const unsigned short*)d_in[0], flag);
  cvt_all_kernel<<<(total + 255) / 256, 256, 0, stream>>>(ca, fin, total, flag);

  // ---- layer 1: C=3, O=64
  xx_kernel<3><<<32, 256, 0, stream>>>(xf, bst1, xxb);
  for (int b0 = 0; b0 < NB; b0 += bpass) {
    pdgemm_kernel<3><<<dim3(32, 32, bpass), 256, 0, stream>>>(xf + b0 * bst1, bst1, xxb + b0 * NPTS, keys);
    select_kernel<<<512 * bpass, 256, 0, stream>>>(keys, idxb + (long)b0 * NPTS * KNN);
  }
  yz_kernel<3><<<dim3(8, 16, NB), 256, 0, stream>>>(xf, bst1, W1f, 64, yb, zb);
  gmax_kernel<<<(NB * 64 * NPTS) / 256, 256, 0, stream>>>(yb, zb, idxb, g1f, b1f, 64, cat, bstc);

  // ---- layer 2: C=64, O=64
  xx_kernel<64><<<32, 256, 0, stream>>>(cat, bstc, xxb);
  for (int b0 = 0; b0 < NB; b0 += bpass) {
    pdgemm_kernel<64><<<dim3(32, 32, bpass), 256, 0, stream>>>(cat + b0 * bstc, bstc, xxb + b0 * NPTS, keys);
    select_kernel<<<512 * bpass, 256, 0, stream>>>(keys, idxb + (long)b0 * NPTS * KNN);
  }
  yz_kernel<64><<<dim3(8, 16, NB), 256, 0, stream>>>(cat, bstc, W2f, 64, yb, zb);
  gmax_kernel<<<(NB * 64 * NPTS) / 256, 256, 0, stream>>>(yb, zb, idxb, g2f, b2f_, 64, cat + 64L * NPTS, bstc);

  // ---- layer 3: C=64, O=128
  xx_kernel<64><<<32, 256, 0, stream>>>(cat + 64L * NPTS, bstc, xxb);
  for (int b0 = 0; b0 < NB; b0 += bpass) {
    pdgemm_kernel<64><<<dim3(32, 32, bpass), 256, 0, stream>>>(cat + 64L * NPTS + b0 * bstc, bstc, xxb + b0 * NPTS, keys);
    select_kernel<<<512 * bpass, 256, 0, stream>>>(keys, idxb + (long)b0 * NPTS * KNN);
  }
  yz_kernel<64><<<dim3(8, 32, NB), 256, 0, stream>>>(cat + 64L * NPTS, bstc, W3f, 128, yb, zb);
  gmax_kernel<<<(NB * 128 * NPTS) / 256, 256, 0, stream>>>(yb, zb, idxb, g3f, b3f, 128, cat + 128L * NPTS, bstc);

  // ---- layer 4: C=128, O=256
  xx_kernel<128><<<32, 256, 0, stream>>>(cat + 128L * NPTS, bstc, xxb);
  for (int b0 = 0; b0 < NB; b0 += bpass) {
    pdgemm_kernel<128><<<dim3(32, 32, bpass), 256, 0, stream>>>(cat + 128L * NPTS + b0 * bstc, bstc, xxb + b0 * NPTS, keys);
    select_kernel<<<512 * bpass, 256, 0, stream>>>(keys, idxb + (long)b0 * NPTS * KNN);
  }
  yz_kernel<128><<<dim3(8, 64, NB), 256, 0, stream>>>(cat + 128L * NPTS, bstc, W4f, 256, yb, zb);
  gmax_kernel<<<(NB * 256 * NPTS) / 256, 256, 0, stream>>>(yb, zb, idxb, g4f, b4f, 256, cat + 256L * NPTS, bstc);

  // ---- conv5 + BN + leaky + global max
  gemm5_kernel<<<dim3(32, 16, NB), 256, 0, stream>>>(cat, W5f, g5f, b5f, pmax);
  reduce5_kernel<<<16, 256, 0, stream>>>(pmax, vb);

  lfnf_kernel<<<NB, 128, 0, stream>>>(lf, nf, W6f, g6f, b6f, W7f, g7f, b7f, vb);

  head1_kernel<<<8, 256, 0, stream>>>(vb, L1f, g8f, b8f, v1b);
  head2_kernel<<<4, 256, 0, stream>>>(v1b, L2f, L2bf, g9f, b9f, v2b);
  head3_kernel<<<1, 128, 0, stream>>>(v2b, L3f, L3bf, d_out, flag);
}

// Round 4
// 1079.159 us; speedup vs baseline: 1.7102x; 1.2694x over previous
//
#include <hip/hip_runtime.h>
#include <hip/hip_bf16.h>

#define NPTS 2048
#define NB 4
#define KNN 32
#define NIN 33

static __device__ __forceinline__ float b2f(__hip_bfloat16 v) { return __bfloat162float(v); }
#define ISQ 0.99999499996875f /* 1/sqrt(1+1e-5) */

// monotone order-preserving key for fp32 (no NaNs): a<b  <=>  ordkey(a)<ordkey(b)
static __device__ __forceinline__ unsigned ordkey(float f) {
  unsigned u = __float_as_uint(f);
  return u ^ (unsigned)(((int)u >> 31) | 0x80000000);
}

static __device__ __forceinline__ void loadv(const float* p, float (&d)[1]) { d[0] = *p; }
static __device__ __forceinline__ void loadv(const float* p, float (&d)[2]) {
  float2 v = *(const float2*)p; d[0] = v.x; d[1] = v.y;
}
static __device__ __forceinline__ void loadv(const float* p, float (&d)[4]) {
  float4 v = *(const float4*)p; d[0] = v.x; d[1] = v.y; d[2] = v.z; d[3] = v.w;
}

// ---- dtype detect: flag=1 if buffer is bf16, 0 if fp32 ----
__global__ __launch_bounds__(64) void detect_kernel(const unsigned short* __restrict__ x,
                                                    int* __restrict__ flag) {
  int cnt = 0;
  for (int i = threadIdx.x; i < 512; i += 64) {
    unsigned e = (x[i] >> 7) & 0xFFu;
    if (e >= 0xC6u) cnt++;
  }
#pragma unroll
  for (int off = 32; off > 0; off >>= 1) cnt += __shfl_down(cnt, off);
  if (threadIdx.x == 0) flag[0] = (cnt == 0) ? 1 : 0;
}

struct CvtArgs {
  const void* src[NIN];
  int off[NIN + 1];
};

__global__ __launch_bounds__(256) void cvt_all_kernel(CvtArgs a, float* __restrict__ out,
                                                      int total, const int* __restrict__ flag) {
  int t = blockIdx.x * 256 + threadIdx.x;
  if (t >= total) return;
  int s = 0;
  while (t >= a.off[s + 1]) s++;
  int j = t - a.off[s];
  float v;
  if (flag[0]) v = b2f(((const __hip_bfloat16*)a.src[s])[j]);
  else         v = ((const float*)a.src[s])[j];
  out[t] = v;
}

// xx[b,m] = sum_c x[b,c,m]^2
template <int C>
__global__ __launch_bounds__(256) void xx_kernel(const float* __restrict__ x, long bstride,
                                                 float* __restrict__ xx) {
  int t = blockIdx.x * 256 + threadIdx.x;
  int b = t / NPTS, m = t % NPTS;
  const float* xb = x + (long)b * bstride + m;
  float s = 0.f;
#pragma unroll
  for (int c = 0; c < C; ++c) { float v = xb[(long)c * NPTS]; s = fmaf(v, v, s); }
  xx[t] = s;
}

// pd-GEMM: keys[b][n][m] = ordkey( (-xx[n] - (-2*dot(x_n,x_m))) - xx[m] )
template <int C>
__global__ __launch_bounds__(256) void pdgemm_kernel(const float* __restrict__ x, long bstride,
                                                     const float* __restrict__ xx,
                                                     unsigned* __restrict__ keys) {
  constexpr int KT = (C < 16) ? C : 16;
  __shared__ __align__(16) float At[KT][64];
  __shared__ __align__(16) float Bt[KT][64];
  int n0 = blockIdx.y * 64, m0 = blockIdx.x * 64;
  int tid = threadIdx.x, tx = tid & 15, ty = tid >> 4;
  const float* xb = x + (long)blockIdx.z * bstride;
  float acc[4][4] = {};
  for (int k0 = 0; k0 < C; k0 += KT) {
    for (int lin = tid; lin < KT * 64; lin += 256) {
      int r = lin >> 6, col = lin & 63;
      At[r][col] = xb[(long)(k0 + r) * NPTS + n0 + col];
      Bt[r][col] = xb[(long)(k0 + r) * NPTS + m0 + col];
    }
    __syncthreads();
#pragma unroll
    for (int kc = 0; kc < KT; ++kc) {
      float4 av = *(const float4*)&At[kc][ty * 4];
      float4 bv = *(const float4*)&Bt[kc][tx * 4];
      acc[0][0] = fmaf(av.x, bv.x, acc[0][0]); acc[0][1] = fmaf(av.x, bv.y, acc[0][1]);
      acc[0][2] = fmaf(av.x, bv.z, acc[0][2]); acc[0][3] = fmaf(av.x, bv.w, acc[0][3]);
      acc[1][0] = fmaf(av.y, bv.x, acc[1][0]); acc[1][1] = fmaf(av.y, bv.y, acc[1][1]);
      acc[1][2] = fmaf(av.y, bv.z, acc[1][2]); acc[1][3] = fmaf(av.y, bv.w, acc[1][3]);
      acc[2][0] = fmaf(av.z, bv.x, acc[2][0]); acc[2][1] = fmaf(av.z, bv.y, acc[2][1]);
      acc[2][2] = fmaf(av.z, bv.z, acc[2][2]); acc[2][3] = fmaf(av.z, bv.w, acc[2][3]);
      acc[3][0] = fmaf(av.w, bv.x, acc[3][0]); acc[3][1] = fmaf(av.w, bv.y, acc[3][1]);
      acc[3][2] = fmaf(av.w, bv.z, acc[3][2]); acc[3][3] = fmaf(av.w, bv.w, acc[3][3]);
    }
    __syncthreads();
  }
  const float* xxq = xx + (long)blockIdx.z * NPTS;
  float4 xxm = *(const float4*)&xxq[m0 + tx * 4];
  unsigned* kb = keys + ((long)blockIdx.z << 22);
#pragma unroll
  for (int i = 0; i < 4; ++i) {
    float xxn = xxq[n0 + ty * 4 + i];
    uint4 o;
    o.x = ordkey((-xxn - (-2.f * acc[i][0])) - xxm.x);
    o.y = ordkey((-xxn - (-2.f * acc[i][1])) - xxm.y);
    o.z = ordkey((-xxn - (-2.f * acc[i][2])) - xxm.z);
    o.w = ordkey((-xxn - (-2.f * acc[i][3])) - xxm.w);
    *(uint4*)&kb[(long)(n0 + ty * 4 + i) * NPTS + m0 + tx * 4] = o;
  }
}

// top-32 select: one wave per query row; u64 keys, lazy top-2, xor-butterfly rounds
__global__ __launch_bounds__(256) void select_kernel(const unsigned* __restrict__ keys,
                                                     int* __restrict__ idxout) {
  int wave = threadIdx.x >> 6, lane = threadIdx.x & 63;
  int q = blockIdx.x * 4 + wave;
  int bloc = q >> 11, n = q & 2047;
  const uint4* rp = (const uint4*)(keys + ((long)((bloc << 11) | n) << 11));
  unsigned long long K[32];
#pragma unroll
  for (int t = 0; t < 8; ++t) {
    uint4 kk = rp[t * 64 + lane];
    unsigned mb = t * 256 + lane * 4;
    K[4 * t + 0] = ((unsigned long long)kk.x << 32) | (unsigned)~(mb + 0);
    K[4 * t + 1] = ((unsigned long long)kk.y << 32) | (unsigned)~(mb + 1);
    K[4 * t + 2] = ((unsigned long long)kk.z << 32) | (unsigned)~(mb + 2);
    K[4 * t + 3] = ((unsigned long long)kk.w << 32) | (unsigned)~(mb + 3);
  }
  unsigned long long a1 = 0, a2 = 0, keep = 0;
#pragma unroll
  for (int s = 0; s < 32; ++s) {
    unsigned long long k = K[s];
    if (k > a1) { a2 = a1; a1 = k; }
    else if (k > a2) a2 = k;
  }
  for (int r = 0; r < KNN; ++r) {
    unsigned long long W = a1;
#pragma unroll
    for (int xm = 32; xm >= 1; xm >>= 1) {
      unsigned long long o = __shfl_xor(W, xm);
      if (o > W) W = o;
    }
    if (lane == r) keep = W;
    if (a1 == W) {
      if (a2) { a1 = a2; a2 = 0; }
      else {
        unsigned long long mx = 0;
#pragma unroll
        for (int s = 0; s < 32; ++s) {
          unsigned long long c = (K[s] < W) ? K[s] : 0ULL;
          mx = c > mx ? c : mx;
        }
        a1 = mx;
      }
    }
  }
  if (lane < KNN)
    idxout[((bloc << 11) | n) * KNN + lane] = (int)(~(unsigned)(keep & 0xFFFFFFFFull));
}

// yzt: point-major GEMM.  yt[b][m][o] = sum_c Wa[o][c] x[b][c][m]
//                         zt[b][m][o] = sum_c (Wb[o][c]-Wa[o][c]) x[b][c][m]
// 64m x 64o tile per block; diff folded into W staging.
template <int C>
__global__ __launch_bounds__(256) void yzt_kernel(const float* __restrict__ x, long bstride,
                                                  const float* __restrict__ W, int O,
                                                  float* __restrict__ yt, float* __restrict__ zt) {
  constexpr int KT = (C < 16) ? C : 16;
  __shared__ __align__(16) float Xs[KT][64];
  __shared__ __align__(16) float Wy[KT][64];
  __shared__ __align__(16) float Wp[KT][64];
  int b = blockIdx.z, m0 = blockIdx.y * 64, o0 = blockIdx.x * 64;
  int tid = threadIdx.x, tx = tid & 15, ty = tid >> 4;
  const float* xb = x + (long)b * bstride;
  const int twoC = 2 * C;
  float accy[4][4] = {}, accp[4][4] = {};
  for (int k0 = 0; k0 < C; k0 += KT) {
    for (int lin = tid; lin < KT * 64; lin += 256) {
      int r = lin >> 6, col = lin & 63;
      Xs[r][col] = xb[(long)(k0 + r) * NPTS + m0 + col];
      float wy = W[(o0 + col) * twoC + k0 + r];
      Wy[r][col] = wy;
      Wp[r][col] = W[(o0 + col) * twoC + C + k0 + r] - wy;
    }
    __syncthreads();
#pragma unroll
    for (int kc = 0; kc < KT; ++kc) {
      float4 wv = *(const float4*)&Wy[kc][tx * 4];
      float4 pv = *(const float4*)&Wp[kc][tx * 4];
      float xm[4];
      xm[0] = Xs[kc][ty * 4 + 0]; xm[1] = Xs[kc][ty * 4 + 1];
      xm[2] = Xs[kc][ty * 4 + 2]; xm[3] = Xs[kc][ty * 4 + 3];
#pragma unroll
      for (int i = 0; i < 4; ++i) {
        accy[i][0] = fmaf(xm[i], wv.x, accy[i][0]);
        accy[i][1] = fmaf(xm[i], wv.y, accy[i][1]);
        accy[i][2] = fmaf(xm[i], wv.z, accy[i][2]);
        accy[i][3] = fmaf(xm[i], wv.w, accy[i][3]);
        accp[i][0] = fmaf(xm[i], pv.x, accp[i][0]);
        accp[i][1] = fmaf(xm[i], pv.y, accp[i][1]);
        accp[i][2] = fmaf(xm[i], pv.z, accp[i][2]);
        accp[i][3] = fmaf(xm[i], pv.w, accp[i][3]);
      }
    }
    __syncthreads();
  }
#pragma unroll
  for (int i = 0; i < 4; ++i) {
    long base = ((long)b * NPTS + m0 + ty * 4 + i) * O + o0 + tx * 4;
    *(float4*)&yt[base] = make_float4(accy[i][0], accy[i][1], accy[i][2], accy[i][3]);
    *(float4*)&zt[base] = make_float4(accp[i][0], accp[i][1], accp[i][2], accp[i][3]);
  }
}

// gmaxt: one wave per query n. lane k holds idx[n,k]; each round broadcasts j via shfl,
// all lanes load yt[b][j][lane*RO..] coalesced. out[b][o][n] channel-major.
template <int RO>
__global__ __launch_bounds__(256) void gmaxt_kernel(const float* __restrict__ yt,
                                                    const float* __restrict__ zt,
                                                    const int* __restrict__ idx,
                                                    const float* __restrict__ g,
                                                    const float* __restrict__ bb,
                                                    float* __restrict__ out, long obstride) {
  constexpr int O = RO * 64;
  int wave = threadIdx.x >> 6, lane = threadIdx.x & 63;
  int n = blockIdx.x * 4 + wave, b = blockIdx.y;
  int jreg = idx[((b << 11) + n) * KNN + (lane & 31)];
  int obase = lane * RO;
  float gs[RO], bs[RO], zr[RO], acc[RO];
  loadv(zt + ((long)(b << 11) + n) * O + obase, zr);
#pragma unroll
  for (int r = 0; r < RO; ++r) {
    gs[r] = g[obase + r] * ISQ;
    bs[r] = bb[obase + r];
    acc[r] = -INFINITY;
  }
  const float* yb = yt + ((long)(b << 11)) * O + obase;
#pragma unroll
  for (int k = 0; k < KNN; ++k) {
    int j = __shfl(jreg, k);
    float yv[RO];
    loadv(yb + (long)j * O, yv);
#pragma unroll
    for (int r = 0; r < RO; ++r) {
      float v = fmaf(gs[r], yv[r] + zr[r], bs[r]);
      v = v >= 0.f ? v : 0.2f * v;
      acc[r] = fmaxf(acc[r], v);
    }
  }
  float* op = out + (long)b * obstride + (long)obase * NPTS + n;
#pragma unroll
  for (int r = 0; r < RO; ++r) op[(long)r * NPTS] = acc[r];
}

// fused W5 GEMM + BN + leaky + partial max over 64-wide n tiles
__global__ __launch_bounds__(256) void gemm5_kernel(const float* __restrict__ cat,
                                                    const float* __restrict__ W5,
                                                    const float* __restrict__ g5,
                                                    const float* __restrict__ b5,
                                                    float* __restrict__ pmax) {
  __shared__ __align__(16) float Al[64][17];
  __shared__ __align__(16) float Bl[16][64];
  __shared__ __align__(16) float red[16][4][16];
  int b = blockIdx.z, po0 = blockIdx.y * 64, n0 = blockIdx.x * 64;
  int tid = threadIdx.x, tx = tid & 15, ty = tid >> 4;
  float acc[4][4] = {};
  const float* catb = cat + (long)b * 512 * NPTS;
  for (int k0 = 0; k0 < 512; k0 += 16) {
#pragma unroll
    for (int i = 0; i < 4; ++i) {
      int lin = tid + i * 256;
      Al[lin >> 4][lin & 15] = W5[(long)(po0 + (lin >> 4)) * 512 + k0 + (lin & 15)];
    }
#pragma unroll
    for (int i = 0; i < 4; ++i) {
      int lin = tid + i * 256;
      Bl[lin >> 6][lin & 63] = catb[(long)(k0 + (lin >> 6)) * NPTS + n0 + (lin & 63)];
    }
    __syncthreads();
#pragma unroll
    for (int kc = 0; kc < 16; ++kc) {
      float a0 = Al[ty * 4 + 0][kc], a1 = Al[ty * 4 + 1][kc];
      float a2 = Al[ty * 4 + 2][kc], a3 = Al[ty * 4 + 3][kc];
      float4 bv = *(const float4*)&Bl[kc][tx * 4];
      acc[0][0] = fmaf(a0, bv.x, acc[0][0]); acc[0][1] = fmaf(a0, bv.y, acc[0][1]);
      acc[0][2] = fmaf(a0, bv.z, acc[0][2]); acc[0][3] = fmaf(a0, bv.w, acc[0][3]);
      acc[1][0] = fmaf(a1, bv.x, acc[1][0]); acc[1][1] = fmaf(a1, bv.y, acc[1][1]);
      acc[1][2] = fmaf(a1, bv.z, acc[1][2]); acc[1][3] = fmaf(a1, bv.w, acc[1][3]);
      acc[2][0] = fmaf(a2, bv.x, acc[2][0]); acc[2][1] = fmaf(a2, bv.y, acc[2][1]);
      acc[2][2] = fmaf(a2, bv.z, acc[2][2]); acc[2][3] = fmaf(a2, bv.w, acc[2][3]);
      acc[3][0] = fmaf(a3, bv.x, acc[3][0]); acc[3][1] = fmaf(a3, bv.y, acc[3][1]);
      acc[3][2] = fmaf(a3, bv.z, acc[3][2]); acc[3][3] = fmaf(a3, bv.w, acc[3][3]);
    }
    __syncthreads();
  }
#pragma unroll
  for (int i = 0; i < 4; ++i) {
    int po = po0 + ty * 4 + i;
    float sc = g5[po] * ISQ;
    float bi = b5[po];
    float mx = -INFINITY;
#pragma unroll
    for (int j = 0; j < 4; ++j) {
      float v = fmaf(sc, acc[i][j], bi);
      v = v >= 0.f ? v : 0.2f * v;
      mx = fmaxf(mx, v);
    }
    red[ty][i][tx] = mx;
  }
  __syncthreads();
  if (tid < 64) {
    float mx = red[tid >> 2][tid & 3][0];
#pragma unroll
    for (int t2 = 1; t2 < 16; ++t2) mx = fmaxf(mx, red[tid >> 2][tid & 3][t2]);
    pmax[(long)(b * 1024 + po0 + tid) * 32 + blockIdx.x] = mx;
  }
}

__global__ __launch_bounds__(256) void reduce5_kernel(const float* __restrict__ pmax,
                                                      float* __restrict__ v) {
  int t = blockIdx.x * 256 + threadIdx.x;
  float mx = -INFINITY;
#pragma unroll
  for (int j = 0; j < 32; ++j) mx = fmaxf(mx, pmax[(long)t * 32 + j]);
  int b = t >> 10, po = t & 1023;
  v[b * 1152 + po] = mx;
}

__global__ __launch_bounds__(128) void lfnf_kernel(const float* __restrict__ l,
                                                   const float* __restrict__ nn,
                                                   const float* __restrict__ W6,
                                                   const float* __restrict__ g6,
                                                   const float* __restrict__ b6,
                                                   const float* __restrict__ W7,
                                                   const float* __restrict__ g7,
                                                   const float* __restrict__ b7,
                                                   float* __restrict__ v) {
  int b = blockIdx.x, t = threadIdx.x;
  if (t < 64) {
    float s = 0.f;
#pragma unroll
    for (int c = 0; c < 5; ++c) s = fmaf(W6[t * 5 + c], l[b * 5 + c], s);
    float val = fmaf(g6[t] * ISQ, s, b6[t]);
    v[b * 1152 + 1024 + t] = val >= 0.f ? val : 0.2f * val;
  } else {
    int o = t - 64;
    float s = 0.f;
#pragma unroll
    for (int c = 0; c < 7; ++c) s = fmaf(W7[o * 7 + c], nn[b * 7 + c], s);
    float val = fmaf(g7[o] * ISQ, s, b7[o]);
    v[b * 1152 + 1088 + o] = val >= 0.f ? val : 0.2f * val;
  }
}

__global__ __launch_bounds__(256) void head1_kernel(const float* __restrict__ v,
                                                    const float* __restrict__ L1,
                                                    const float* __restrict__ g8,
                                                    const float* __restrict__ b8,
                                                    float* __restrict__ v1) {
  int t = blockIdx.x * 256 + threadIdx.x;
  int b = t >> 9, o = t & 511;
  const float* vb = v + b * 1152;
  const float* wr = L1 + (long)o * 1152;
  float s = 0.f;
#pragma unroll 4
  for (int c = 0; c < 1152; ++c) s = fmaf(wr[c], vb[c], s);
  float val = fmaf(g8[o] * ISQ, s, b8[o]);
  v1[t] = fmaxf(val, 0.f);
}

__global__ __launch_bounds__(256) void head2_kernel(const float* __restrict__ v1,
                                                    const float* __restrict__ L2,
                                                    const float* __restrict__ L2b,
                                                    const float* __restrict__ g9,
                                                    const float* __restrict__ b9,
                                                    float* __restrict__ v2) {
  int t = blockIdx.x * 256 + threadIdx.x;
  int b = t >> 8, o = t & 255;
  const float* vb = v1 + b * 512;
  const float* wr = L2 + (long)o * 512;
  float s = 0.f;
#pragma unroll 4
  for (int c = 0; c < 512; ++c) s = fmaf(wr[c], vb[c], s);
  s += L2b[o];
  float val = fmaf(g9[o] * ISQ, s, b9[o]);
  v2[t] = fmaxf(val, 0.f);
}

__global__ __launch_bounds__(128) void head3_kernel(const float* __restrict__ v2,
                                                    const float* __restrict__ L3,
                                                    const float* __restrict__ L3b,
                                                    void* __restrict__ out,
                                                    const int* __restrict__ flag) {
  int t = threadIdx.x;
  if (t >= 112) return;
  int b = t / 28, o = t % 28;
  const float* vb = v2 + b * 256;
  const float* wr = L3 + o * 256;
  float s = 0.f;
#pragma unroll 4
  for (int c = 0; c < 256; ++c) s = fmaf(wr[c], vb[c], s);
  s += L3b[o];
  if (flag[0]) ((__hip_bfloat16*)out)[t] = __float2bfloat16(s);
  else         ((float*)out)[t] = s;
}

extern "C" void kernel_launch(void* const* d_in, const int* in_sizes, int n_in,
                              void* d_out, int out_size, void* d_ws, size_t ws_size,
                              hipStream_t stream) {
  CvtArgs ca;
  int off[NIN + 1];
  off[0] = 0;
  for (int i = 0; i < NIN; ++i) {
    ca.src[i] = d_in[i];
    off[i + 1] = off[i] + in_sizes[i];
    ca.off[i] = off[i];
  }
  ca.off[NIN] = off[NIN];
  const int total = off[NIN];

  int* flag = (int*)d_ws;
  float* fin = (float*)((char*)d_ws + 64);
  const float* xf  = fin + off[0];
  const float* lf  = fin + off[1];
  const float* nf  = fin + off[2];
  const float* W1f = fin + off[3];  const float* g1f = fin + off[4];  const float* b1f = fin + off[5];
  const float* W2f = fin + off[6];  const float* g2f = fin + off[7];  const float* b2f_ = fin + off[8];
  const float* W3f = fin + off[9];  const float* g3f = fin + off[10]; const float* b3f = fin + off[11];
  const float* W4f = fin + off[12]; const float* g4f = fin + off[13]; const float* b4f = fin + off[14];
  const float* W5f = fin + off[15]; const float* g5f = fin + off[16]; const float* b5f = fin + off[17];
  const float* W6f = fin + off[18]; const float* g6f = fin + off[19]; const float* b6f = fin + off[20];
  const float* W7f = fin + off[21]; const float* g7f = fin + off[22]; const float* b7f = fin + off[23];
  const float* L1f = fin + off[24]; const float* g8f = fin + off[25]; const float* b8f = fin + off[26];
  const float* L2f = fin + off[27]; const float* L2bf = fin + off[28];
  const float* g9f = fin + off[29]; const float* b9f = fin + off[30];
  const float* L3f = fin + off[31]; const float* L3bf = fin + off[32];

  float* p = fin + ((total + 15) & ~15);
  float* cat  = p;                               // 4*512*2048
  float* yb   = cat + 4 * 512 * NPTS;            // 4*2048*256 (point-major)
  float* zb   = yb + 4 * 256 * NPTS;             // 4*2048*256 (point-major)
  float* xxb  = zb + 4 * 256 * NPTS;             // 4*2048
  int*   idxb = (int*)(xxb + 4 * NPTS);          // 4*2048*32
  float* pmax = (float*)(idxb + 4 * NPTS * KNN); // 4*1024*32
  float* vb   = pmax + 4 * 1024 * 32;            // 4*1152
  float* v1b  = vb + 4 * 1152;                   // 4*512
  float* v2b  = v1b + 4 * 512;                   // 4*256
  unsigned* keys_tail = (unsigned*)(v2b + 4 * 256);

  // keys: 4 batches at tail if ws allows, else 1 batch overlaid on yb/zb (dead there)
  size_t need_full = (size_t)((char*)(keys_tail + (size_t)NB * NPTS * NPTS) - (char*)d_ws);
  int bpass = (ws_size >= need_full) ? NB : 1;
  unsigned* keys = (bpass == NB) ? keys_tail : (unsigned*)yb;

  const long bst1 = 3L * NPTS;
  const long bstc = 512L * NPTS;

  detect_kernel<<<1, 64, 0, stream>>>((const unsigned short*)d_in[0], flag);
  cvt_all_kernel<<<(total + 255) / 256, 256, 0, stream>>>(ca, fin, total, flag);

  // ---- layer 1: C=3, O=64
  xx_kernel<3><<<32, 256, 0, stream>>>(xf, bst1, xxb);
  for (int b0 = 0; b0 < NB; b0 += bpass) {
    pdgemm_kernel<3><<<dim3(32, 32, bpass), 256, 0, stream>>>(xf + b0 * bst1, bst1, xxb + b0 * NPTS, keys);
    select_kernel<<<512 * bpass, 256, 0, stream>>>(keys, idxb + (long)b0 * NPTS * KNN);
  }
  yzt_kernel<3><<<dim3(1, 32, NB), 256, 0, stream>>>(xf, bst1, W1f, 64, yb, zb);
  gmaxt_kernel<1><<<dim3(512, NB), 256, 0, stream>>>(yb, zb, idxb, g1f, b1f, cat, bstc);

  // ---- layer 2: C=64, O=64
  xx_kernel<64><<<32, 256, 0, stream>>>(cat, bstc, xxb);
  for (int b0 = 0; b0 < NB; b0 += bpass) {
    pdgemm_kernel<64><<<dim3(32, 32, bpass), 256, 0, stream>>>(cat + b0 * bstc, bstc, xxb + b0 * NPTS, keys);
    select_kernel<<<512 * bpass, 256, 0, stream>>>(keys, idxb + (long)b0 * NPTS * KNN);
  }
  yzt_kernel<64><<<dim3(1, 32, NB), 256, 0, stream>>>(cat, bstc, W2f, 64, yb, zb);
  gmaxt_kernel<1><<<dim3(512, NB), 256, 0, stream>>>(yb, zb, idxb, g2f, b2f_, cat + 64L * NPTS, bstc);

  // ---- layer 3: C=64, O=128
  xx_kernel<64><<<32, 256, 0, stream>>>(cat + 64L * NPTS, bstc, xxb);
  for (int b0 = 0; b0 < NB; b0 += bpass) {
    pdgemm_kernel<64><<<dim3(32, 32, bpass), 256, 0, stream>>>(cat + 64L * NPTS + b0 * bstc, bstc, xxb + b0 * NPTS, keys);
    select_kernel<<<512 * bpass, 256, 0, stream>>>(keys, idxb + (long)b0 * NPTS * KNN);
  }
  yzt_kernel<64><<<dim3(2, 32, NB), 256, 0, stream>>>(cat + 64L * NPTS, bstc, W3f, 128, yb, zb);
  gmaxt_kernel<2><<<dim3(512, NB), 256, 0, stream>>>(yb, zb, idxb, g3f, b3f, cat + 128L * NPTS, bstc);

  // ---- layer 4: C=128, O=256
  xx_kernel<128><<<32, 256, 0, stream>>>(cat + 128L * NPTS, bstc, xxb);
  for (int b0 = 0; b0 < NB; b0 += bpass) {
    pdgemm_kernel<128><<<dim3(32, 32, bpass), 256, 0, stream>>>(cat + 128L * NPTS + b0 * bstc, bstc, xxb + b0 * NPTS, keys);
    select_kernel<<<512 * bpass, 256, 0, stream>>>(keys, idxb + (long)b0 * NPTS * KNN);
  }
  yzt_kernel<128><<<dim3(4, 32, NB), 256, 0, stream>>>(cat + 128L * NPTS, bstc, W4f, 256, yb, zb);
  gmaxt_kernel<4><<<dim3(512, NB), 256, 0, stream>>>(yb, zb, idxb, g4f, b4f, cat + 256L * NPTS, bstc);

  // ---- conv5 + BN + leaky + global max
  gemm5_kernel<<<dim3(32, 16, NB), 256, 0, stream>>>(cat, W5f, g5f, b5f, pmax);
  reduce5_kernel<<<16, 256, 0, stream>>>(pmax, vb);

  lfnf_kernel<<<NB, 128, 0, stream>>>(lf, nf, W6f, g6f, b6f, W7f, g7f, b7f, vb);

  head1_kernel<<<8, 256, 0, stream>>>(vb, L1f, g8f, b8f, v1b);
  head2_kernel<<<4, 256, 0, stream>>>(v1b, L2f, L2bf, g9f, b9f, v2b);
  head3_kernel<<<1, 128, 0, stream>>>(v2b, L3f, L3bf, d_out, flag);
}

// Round 5
// 876.464 us; speedup vs baseline: 2.1057x; 1.2313x over previous
//
#include <hip/hip_runtime.h>
#include <hip/hip_bf16.h>

#define NPTS 2048
#define NB 4
#define KNN 32
#define NIN 33

static __device__ __forceinline__ float b2f(__hip_bfloat16 v) { return __bfloat162float(v); }
#define ISQ 0.99999499996875f /* 1/sqrt(1+1e-5) */

// monotone order-preserving key for fp32 (no NaNs): a<b  <=>  ordkey(a)<ordkey(b)
static __device__ __forceinline__ unsigned ordkey(float f) {
  unsigned u = __float_as_uint(f);
  return u ^ (unsigned)(((int)u >> 31) | 0x80000000);
}

static __device__ __forceinline__ void loadv(const float* p, float (&d)[1]) { d[0] = *p; }
static __device__ __forceinline__ void loadv(const float* p, float (&d)[2]) {
  float2 v = *(const float2*)p; d[0] = v.x; d[1] = v.y;
}
static __device__ __forceinline__ void loadv(const float* p, float (&d)[4]) {
  float4 v = *(const float4*)p; d[0] = v.x; d[1] = v.y; d[2] = v.z; d[3] = v.w;
}

static __device__ __forceinline__ float wave_red_sum(float s) {
#pragma unroll
  for (int off = 32; off > 0; off >>= 1) s += __shfl_xor(s, off);
  return s;
}

// ---- dtype detect: flag=1 if buffer is bf16, 0 if fp32 ----
__global__ __launch_bounds__(64) void detect_kernel(const unsigned short* __restrict__ x,
                                                    int* __restrict__ flag) {
  int cnt = 0;
  for (int i = threadIdx.x; i < 512; i += 64) {
    unsigned e = (x[i] >> 7) & 0xFFu;
    if (e >= 0xC6u) cnt++;
  }
#pragma unroll
  for (int off = 32; off > 0; off >>= 1) cnt += __shfl_down(cnt, off);
  if (threadIdx.x == 0) flag[0] = (cnt == 0) ? 1 : 0;
}

struct CvtArgs {
  const void* src[NIN];
  int off[NIN + 1];
};

__global__ __launch_bounds__(256) void cvt_all_kernel(CvtArgs a, float* __restrict__ out,
                                                      int total, const int* __restrict__ flag) {
  int t = blockIdx.x * 256 + threadIdx.x;
  if (t >= total) return;
  int s = 0;
  while (t >= a.off[s + 1]) s++;
  int j = t - a.off[s];
  float v;
  if (flag[0]) v = b2f(((const __hip_bfloat16*)a.src[s])[j]);
  else         v = ((const float*)a.src[s])[j];
  out[t] = v;
}

// xx[b,m] = sum_c x[b,c,m]^2  (only needed for layer-1 raw input)
template <int C>
__global__ __launch_bounds__(256) void xx_kernel(const float* __restrict__ x, long bstride,
                                                 float* __restrict__ xx) {
  int t = blockIdx.x * 256 + threadIdx.x;
  int b = t / NPTS, m = t % NPTS;
  const float* xb = x + (long)b * bstride + m;
  float s = 0.f;
#pragma unroll
  for (int c = 0; c < C; ++c) { float v = xb[(long)c * NPTS]; s = fmaf(v, v, s); }
  xx[t] = s;
}

// symmetric pd-GEMM: pd[n][m] = (-xx[n] - (-2*dot)) - xx[m]; triangular tile grid,
// off-diagonal blocks write straight tile + LDS-transposed mirror tile.
template <int C>
__global__ __launch_bounds__(256) void pdgemmsym_kernel(const float* __restrict__ x, long bstride,
                                                        const float* __restrict__ xx,
                                                        unsigned* __restrict__ keys) {
  constexpr int KT = (C < 16) ? C : 16;
  __shared__ __align__(16) float At[KT][64];
  __shared__ __align__(16) float Bt[KT][64];
  __shared__ __align__(16) unsigned Ts[64][68];
  int t = blockIdx.x;
  int tj = (int)((sqrtf(8.f * (float)t + 1.f) - 1.f) * 0.5f);
  while ((tj + 1) * (tj + 2) / 2 <= t) tj++;
  while (tj * (tj + 1) / 2 > t) tj--;
  int ti = t - tj * (tj + 1) / 2;            // ti <= tj
  int n0 = ti * 64, m0 = tj * 64;
  int tid = threadIdx.x, tx = tid & 15, ty = tid >> 4;
  const float* xb = x + (long)blockIdx.y * bstride;
  float acc[4][4] = {};
  for (int k0 = 0; k0 < C; k0 += KT) {
    for (int lin = tid; lin < KT * 64; lin += 256) {
      int r = lin >> 6, col = lin & 63;
      At[r][col] = xb[(long)(k0 + r) * NPTS + n0 + col];
      Bt[r][col] = xb[(long)(k0 + r) * NPTS + m0 + col];
    }
    __syncthreads();
#pragma unroll
    for (int kc = 0; kc < KT; ++kc) {
      float4 av = *(const float4*)&At[kc][ty * 4];
      float4 bv = *(const float4*)&Bt[kc][tx * 4];
      acc[0][0] = fmaf(av.x, bv.x, acc[0][0]); acc[0][1] = fmaf(av.x, bv.y, acc[0][1]);
      acc[0][2] = fmaf(av.x, bv.z, acc[0][2]); acc[0][3] = fmaf(av.x, bv.w, acc[0][3]);
      acc[1][0] = fmaf(av.y, bv.x, acc[1][0]); acc[1][1] = fmaf(av.y, bv.y, acc[1][1]);
      acc[1][2] = fmaf(av.y, bv.z, acc[1][2]); acc[1][3] = fmaf(av.y, bv.w, acc[1][3]);
      acc[2][0] = fmaf(av.z, bv.x, acc[2][0]); acc[2][1] = fmaf(av.z, bv.y, acc[2][1]);
      acc[2][2] = fmaf(av.z, bv.z, acc[2][2]); acc[2][3] = fmaf(av.z, bv.w, acc[2][3]);
      acc[3][0] = fmaf(av.w, bv.x, acc[3][0]); acc[3][1] = fmaf(av.w, bv.y, acc[3][1]);
      acc[3][2] = fmaf(av.w, bv.z, acc[3][2]); acc[3][3] = fmaf(av.w, bv.w, acc[3][3]);
    }
    __syncthreads();
  }
  const float* xxq = xx + (long)blockIdx.y * NPTS;
  float4 xxm = *(const float4*)&xxq[m0 + tx * 4];
  unsigned* kb = keys + ((long)blockIdx.y << 22);
  unsigned ok[4][4];
#pragma unroll
  for (int i = 0; i < 4; ++i) {
    float xxn = xxq[n0 + ty * 4 + i];
    ok[i][0] = ordkey((-xxn - (-2.f * acc[i][0])) - xxm.x);
    ok[i][1] = ordkey((-xxn - (-2.f * acc[i][1])) - xxm.y);
    ok[i][2] = ordkey((-xxn - (-2.f * acc[i][2])) - xxm.z);
    ok[i][3] = ordkey((-xxn - (-2.f * acc[i][3])) - xxm.w);
    uint4 o = make_uint4(ok[i][0], ok[i][1], ok[i][2], ok[i][3]);
    *(uint4*)&kb[(long)(n0 + ty * 4 + i) * NPTS + m0 + tx * 4] = o;
  }
  if (ti != tj) {
#pragma unroll
    for (int i = 0; i < 4; ++i)
#pragma unroll
      for (int j = 0; j < 4; ++j) Ts[tx * 4 + j][ty * 4 + i] = ok[i][j];
    __syncthreads();
#pragma unroll
    for (int i = 0; i < 4; ++i)
      *(uint4*)&kb[(long)(m0 + ty * 4 + i) * NPTS + n0 + tx * 4] =
          *(const uint4*)&Ts[ty * 4 + i][tx * 4];
  }
}

// top-32 select: one wave per query row; u64 keys, lazy top-2, xor-butterfly rounds
__global__ __launch_bounds__(256) void select_kernel(const unsigned* __restrict__ keys,
                                                     int* __restrict__ idxout) {
  int wave = threadIdx.x >> 6, lane = threadIdx.x & 63;
  int q = blockIdx.x * 4 + wave;
  int bloc = q >> 11, n = q & 2047;
  const uint4* rp = (const uint4*)(keys + ((long)((bloc << 11) | n) << 11));
  unsigned long long K[32];
#pragma unroll
  for (int t = 0; t < 8; ++t) {
    uint4 kk = rp[t * 64 + lane];
    unsigned mb = t * 256 + lane * 4;
    K[4 * t + 0] = ((unsigned long long)kk.x << 32) | (unsigned)~(mb + 0);
    K[4 * t + 1] = ((unsigned long long)kk.y << 32) | (unsigned)~(mb + 1);
    K[4 * t + 2] = ((unsigned long long)kk.z << 32) | (unsigned)~(mb + 2);
    K[4 * t + 3] = ((unsigned long long)kk.w << 32) | (unsigned)~(mb + 3);
  }
  unsigned long long a1 = 0, a2 = 0, keep = 0;
#pragma unroll
  for (int s = 0; s < 32; ++s) {
    unsigned long long k = K[s];
    if (k > a1) { a2 = a1; a1 = k; }
    else if (k > a2) a2 = k;
  }
  for (int r = 0; r < KNN; ++r) {
    unsigned long long W = a1;
#pragma unroll
    for (int xm = 32; xm >= 1; xm >>= 1) {
      unsigned long long o = __shfl_xor(W, xm);
      if (o > W) W = o;
    }
    if (lane == r) keep = W;
    if (a1 == W) {
      if (a2) { a1 = a2; a2 = 0; }
      else {
        unsigned long long mx = 0;
#pragma unroll
        for (int s = 0; s < 32; ++s) {
          unsigned long long c = (K[s] < W) ? K[s] : 0ULL;
          mx = c > mx ? c : mx;
        }
        a1 = mx;
      }
    }
  }
  if (lane < KNN)
    idxout[((bloc << 11) | n) * KNN + lane] = (int)(~(unsigned)(keep & 0xFFFFFFFFull));
}

// yzt: point-major GEMM.  yt[b][m][o] = sum_c Wa[o][c] x[b][c][m]
//                         zt[b][m][o] = sum_c (Wb[o][c]-Wa[o][c]) x[b][c][m]
template <int C>
__global__ __launch_bounds__(256) void yzt_kernel(const float* __restrict__ x, long bstride,
                                                  const float* __restrict__ W, int O,
                                                  float* __restrict__ yt, float* __restrict__ zt) {
  constexpr int KT = (C < 16) ? C : 16;
  __shared__ __align__(16) float Xs[KT][64];
  __shared__ __align__(16) float Wy[KT][64];
  __shared__ __align__(16) float Wp[KT][64];
  int b = blockIdx.z, m0 = blockIdx.y * 64, o0 = blockIdx.x * 64;
  int tid = threadIdx.x, tx = tid & 15, ty = tid >> 4;
  const float* xb = x + (long)b * bstride;
  const int twoC = 2 * C;
  float accy[4][4] = {}, accp[4][4] = {};
  for (int k0 = 0; k0 < C; k0 += KT) {
    for (int lin = tid; lin < KT * 64; lin += 256) {
      int r = lin >> 6, col = lin & 63;
      Xs[r][col] = xb[(long)(k0 + r) * NPTS + m0 + col];
      float wy = W[(o0 + col) * twoC + k0 + r];
      Wy[r][col] = wy;
      Wp[r][col] = W[(o0 + col) * twoC + C + k0 + r] - wy;
    }
    __syncthreads();
#pragma unroll
    for (int kc = 0; kc < KT; ++kc) {
      float4 wv = *(const float4*)&Wy[kc][tx * 4];
      float4 pv = *(const float4*)&Wp[kc][tx * 4];
      float xm[4];
      xm[0] = Xs[kc][ty * 4 + 0]; xm[1] = Xs[kc][ty * 4 + 1];
      xm[2] = Xs[kc][ty * 4 + 2]; xm[3] = Xs[kc][ty * 4 + 3];
#pragma unroll
      for (int i = 0; i < 4; ++i) {
        accy[i][0] = fmaf(xm[i], wv.x, accy[i][0]);
        accy[i][1] = fmaf(xm[i], wv.y, accy[i][1]);
        accy[i][2] = fmaf(xm[i], wv.z, accy[i][2]);
        accy[i][3] = fmaf(xm[i], wv.w, accy[i][3]);
        accp[i][0] = fmaf(xm[i], pv.x, accp[i][0]);
        accp[i][1] = fmaf(xm[i], pv.y, accp[i][1]);
        accp[i][2] = fmaf(xm[i], pv.z, accp[i][2]);
        accp[i][3] = fmaf(xm[i], pv.w, accp[i][3]);
      }
    }
    __syncthreads();
  }
#pragma unroll
  for (int i = 0; i < 4; ++i) {
    long base = ((long)b * NPTS + m0 + ty * 4 + i) * O + o0 + tx * 4;
    *(float4*)&yt[base] = make_float4(accy[i][0], accy[i][1], accy[i][2], accy[i][3]);
    *(float4*)&zt[base] = make_float4(accp[i][0], accp[i][1], accp[i][2], accp[i][3]);
  }
}

// gmaxt: one wave per query n; also emits xx for the next layer (sum over all O of out^2)
template <int RO>
__global__ __launch_bounds__(256) void gmaxt_kernel(const float* __restrict__ yt,
                                                    const float* __restrict__ zt,
                                                    const int* __restrict__ idx,
                                                    const float* __restrict__ g,
                                                    const float* __restrict__ bb,
                                                    float* __restrict__ out, long obstride,
                                                    float* __restrict__ xxout) {
  constexpr int O = RO * 64;
  int wave = threadIdx.x >> 6, lane = threadIdx.x & 63;
  int n = blockIdx.x * 4 + wave, b = blockIdx.y;
  int jreg = idx[((b << 11) + n) * KNN + (lane & 31)];
  int obase = lane * RO;
  float gs[RO], bs[RO], zr[RO], acc[RO];
  loadv(zt + ((long)(b << 11) + n) * O + obase, zr);
#pragma unroll
  for (int r = 0; r < RO; ++r) {
    gs[r] = g[obase + r] * ISQ;
    bs[r] = bb[obase + r];
    acc[r] = -INFINITY;
  }
  const float* yb = yt + ((long)(b << 11)) * O + obase;
#pragma unroll
  for (int k = 0; k < KNN; ++k) {
    int j = __shfl(jreg, k);
    float yv[RO];
    loadv(yb + (long)j * O, yv);
#pragma unroll
    for (int r = 0; r < RO; ++r) {
      float v = fmaf(gs[r], yv[r] + zr[r], bs[r]);
      v = v >= 0.f ? v : 0.2f * v;
      acc[r] = fmaxf(acc[r], v);
    }
  }
  float* op = out + (long)b * obstride + (long)obase * NPTS + n;
#pragma unroll
  for (int r = 0; r < RO; ++r) op[(long)r * NPTS] = acc[r];
  if (xxout) {
    float ss = 0.f;
#pragma unroll
    for (int r = 0; r < RO; ++r) ss = fmaf(acc[r], acc[r], ss);
    ss = wave_red_sum(ss);
    if (lane == 0) xxout[(b << 11) + n] = ss;
  }
}

// fused W5 GEMM + BN + leaky + partial max; 128po x 128n tile, 8x8 micro
__global__ __launch_bounds__(256) void gemm5_kernel(const float* __restrict__ cat,
                                                    const float* __restrict__ W5,
                                                    const float* __restrict__ g5,
                                                    const float* __restrict__ b5,
                                                    float* __restrict__ pmax) {
  __shared__ __align__(16) float As[16][132];
  __shared__ __align__(16) float Bs[16][132];
  __shared__ __align__(16) float red[16][8][16];
  int b = blockIdx.z, po0 = blockIdx.y * 128, n0 = blockIdx.x * 128;
  int tid = threadIdx.x, tx = tid & 15, ty = tid >> 4;
  float acc[8][8] = {};
  const float* catb = cat + (long)b * 512 * NPTS;
  for (int k0 = 0; k0 < 512; k0 += 16) {
#pragma unroll
    for (int i = 0; i < 8; ++i) {
      int lin = tid + i * 256;
      int k = lin & 15, pp = lin >> 4;
      As[k][pp] = W5[(long)(po0 + pp) * 512 + k0 + k];
    }
#pragma unroll
    for (int i = 0; i < 8; ++i) {
      int lin = tid + i * 256;
      int k = lin >> 7, nn = lin & 127;
      Bs[k][nn] = catb[(long)(k0 + k) * NPTS + n0 + nn];
    }
    __syncthreads();
#pragma unroll
    for (int kc = 0; kc < 16; ++kc) {
      float a[8], bvv[8];
      loadv(&As[kc][ty * 8 + 0], *(float(*)[4])&a[0]);
      loadv(&As[kc][ty * 8 + 4], *(float(*)[4])&a[4]);
      loadv(&Bs[kc][tx * 8 + 0], *(float(*)[4])&bvv[0]);
      loadv(&Bs[kc][tx * 8 + 4], *(float(*)[4])&bvv[4]);
#pragma unroll
      for (int i = 0; i < 8; ++i)
#pragma unroll
        for (int j = 0; j < 8; ++j) acc[i][j] = fmaf(a[i], bvv[j], acc[i][j]);
    }
    __syncthreads();
  }
#pragma unroll
  for (int i = 0; i < 8; ++i) {
    int po = po0 + ty * 8 + i;
    float sc = g5[po] * ISQ;
    float bi = b5[po];
    float mx = -INFINITY;
#pragma unroll
    for (int j = 0; j < 8; ++j) {
      float v = fmaf(sc, acc[i][j], bi);
      v = v >= 0.f ? v : 0.2f * v;
      mx = fmaxf(mx, v);
    }
    red[ty][i][tx] = mx;
  }
  __syncthreads();
  if (tid < 128) {
    int tyr = tid >> 3, ir = tid & 7;
    float mx = red[tyr][ir][0];
#pragma unroll
    for (int t2 = 1; t2 < 16; ++t2) mx = fmaxf(mx, red[tyr][ir][t2]);
    pmax[(long)(b * 1024 + po0 + tid) * 16 + blockIdx.x] = mx;
  }
}

__global__ __launch_bounds__(256) void reduce5_kernel(const float* __restrict__ pmax,
                                                      float* __restrict__ v) {
  int t = blockIdx.x * 256 + threadIdx.x;
  float mx = -INFINITY;
#pragma unroll
  for (int j = 0; j < 16; ++j) mx = fmaxf(mx, pmax[(long)t * 16 + j]);
  int b = t >> 10, po = t & 1023;
  v[b * 1152 + po] = mx;
}

__global__ __launch_bounds__(128) void lfnf_kernel(const float* __restrict__ l,
                                                   const float* __restrict__ nn,
                                                   const float* __restrict__ W6,
                                                   const float* __restrict__ g6,
                                                   const float* __restrict__ b6,
                                                   const float* __restrict__ W7,
                                                   const float* __restrict__ g7,
                                                   const float* __restrict__ b7,
                                                   float* __restrict__ v) {
  int b = blockIdx.x, t = threadIdx.x;
  if (t < 64) {
    float s = 0.f;
#pragma unroll
    for (int c = 0; c < 5; ++c) s = fmaf(W6[t * 5 + c], l[b * 5 + c], s);
    float val = fmaf(g6[t] * ISQ, s, b6[t]);
    v[b * 1152 + 1024 + t] = val >= 0.f ? val : 0.2f * val;
  } else {
    int o = t - 64;
    float s = 0.f;
#pragma unroll
    for (int c = 0; c < 7; ++c) s = fmaf(W7[o * 7 + c], nn[b * 7 + c], s);
    float val = fmaf(g7[o] * ISQ, s, b7[o]);
    v[b * 1152 + 1088 + o] = val >= 0.f ? val : 0.2f * val;
  }
}

// one wave per output row; lane-strided dot + shuffle reduce
__global__ __launch_bounds__(256) void head1_kernel(const float* __restrict__ v,
                                                    const float* __restrict__ L1,
                                                    const float* __restrict__ g8,
                                                    const float* __restrict__ b8,
                                                    float* __restrict__ v1) {
  int wave = threadIdx.x >> 6, lane = threadIdx.x & 63;
  int t = blockIdx.x * 4 + wave;   // b*512 + o  (2048)
  int b = t >> 9, o = t & 511;
  const float* vb = v + b * 1152;
  const float* wr = L1 + (long)o * 1152;
  float s = 0.f;
#pragma unroll
  for (int c = lane; c < 1152; c += 64) s = fmaf(wr[c], vb[c], s);
  s = wave_red_sum(s);
  if (lane == 0) {
    float val = fmaf(g8[o] * ISQ, s, b8[o]);
    v1[t] = fmaxf(val, 0.f);
  }
}

__global__ __launch_bounds__(256) void head2_kernel(const float* __restrict__ v1,
                                                    const float* __restrict__ L2,
                                                    const float* __restrict__ L2b,
                                                    const float* __restrict__ g9,
                                                    const float* __restrict__ b9,
                                                    float* __restrict__ v2) {
  int wave = threadIdx.x >> 6, lane = threadIdx.x & 63;
  int t = blockIdx.x * 4 + wave;   // b*256 + o  (1024)
  int b = t >> 8, o = t & 255;
  const float* vb = v1 + b * 512;
  const float* wr = L2 + (long)o * 512;
  float s = 0.f;
#pragma unroll
  for (int c = lane; c < 512; c += 64) s = fmaf(wr[c], vb[c], s);
  s = wave_red_sum(s);
  if (lane == 0) {
    float sv = s + L2b[o];
    float val = fmaf(g9[o] * ISQ, sv, b9[o]);
    v2[t] = fmaxf(val, 0.f);
  }
}

__global__ __launch_bounds__(256) void head3_kernel(const float* __restrict__ v2,
                                                    const float* __restrict__ L3,
                                                    const float* __restrict__ L3b,
                                                    void* __restrict__ out,
                                                    const int* __restrict__ flag) {
  int wave = threadIdx.x >> 6, lane = threadIdx.x & 63;
  int t = blockIdx.x * 4 + wave;   // b*28 + o  (112)
  if (t >= 112) return;
  int b = t / 28, o = t % 28;
  const float* vb = v2 + b * 256;
  const float* wr = L3 + o * 256;
  float s = 0.f;
#pragma unroll
  for (int c = lane; c < 256; c += 64) s = fmaf(wr[c], vb[c], s);
  s = wave_red_sum(s);
  if (lane == 0) {
    float sv = s + L3b[o];
    if (flag[0]) ((__hip_bfloat16*)out)[t] = __float2bfloat16(sv);
    else         ((float*)out)[t] = sv;
  }
}

extern "C" void kernel_launch(void* const* d_in, const int* in_sizes, int n_in,
                              void* d_out, int out_size, void* d_ws, size_t ws_size,
                              hipStream_t stream) {
  CvtArgs ca;
  int off[NIN + 1];
  off[0] = 0;
  for (int i = 0; i < NIN; ++i) {
    ca.src[i] = d_in[i];
    off[i + 1] = off[i] + in_sizes[i];
    ca.off[i] = off[i];
  }
  ca.off[NIN] = off[NIN];
  const int total = off[NIN];

  int* flag = (int*)d_ws;
  float* fin = (float*)((char*)d_ws + 64);
  const float* xf  = fin + off[0];
  const float* lf  = fin + off[1];
  const float* nf  = fin + off[2];
  const float* W1f = fin + off[3];  const float* g1f = fin + off[4];  const float* b1f = fin + off[5];
  const float* W2f = fin + off[6];  const float* g2f = fin + off[7];  const float* b2f_ = fin + off[8];
  const float* W3f = fin + off[9];  const float* g3f = fin + off[10]; const float* b3f = fin + off[11];
  const float* W4f = fin + off[12]; const float* g4f = fin + off[13]; const float* b4f = fin + off[14];
  const float* W5f = fin + off[15]; const float* g5f = fin + off[16]; const float* b5f = fin + off[17];
  const float* W6f = fin + off[18]; const float* g6f = fin + off[19]; const float* b6f = fin + off[20];
  const float* W7f = fin + off[21]; const float* g7f = fin + off[22]; const float* b7f = fin + off[23];
  const float* L1f = fin + off[24]; const float* g8f = fin + off[25]; const float* b8f = fin + off[26];
  const float* L2f = fin + off[27]; const float* L2bf = fin + off[28];
  const float* g9f = fin + off[29]; const float* b9f = fin + off[30];
  const float* L3f = fin + off[31]; const float* L3bf = fin + off[32];

  float* p = fin + ((total + 15) & ~15);
  float* cat  = p;                               // 4*512*2048
  float* yb   = cat + 4 * 512 * NPTS;            // 4*2048*256 (point-major)
  float* zb   = yb + 4 * 256 * NPTS;             // 4*2048*256 (point-major)
  float* xxb  = zb + 4 * 256 * NPTS;             // 4*2048
  int*   idxb = (int*)(xxb + 4 * NPTS);          // 4*2048*32
  float* pmax = (float*)(idxb + 4 * NPTS * KNN); // 4*1024*32 (16 used)
  float* vb   = pmax + 4 * 1024 * 32;            // 4*1152
  float* v1b  = vb + 4 * 1152;                   // 4*512
  float* v2b  = v1b + 4 * 512;                   // 4*256
  unsigned* keys_tail = (unsigned*)(v2b + 4 * 256);

  size_t need_full = (size_t)((char*)(keys_tail + (size_t)NB * NPTS * NPTS) - (char*)d_ws);
  int bpass = (ws_size >= need_full) ? NB : 1;
  unsigned* keys = (bpass == NB) ? keys_tail : (unsigned*)yb;

  const long bst1 = 3L * NPTS;
  const long bstc = 512L * NPTS;
  const int NTRI = 32 * 33 / 2;   // 528 triangular tiles

  detect_kernel<<<1, 64, 0, stream>>>((const unsigned short*)d_in[0], flag);
  cvt_all_kernel<<<(total + 255) / 256, 256, 0, stream>>>(ca, fin, total, flag);

  // ---- layer 1: C=3, O=64
  xx_kernel<3><<<32, 256, 0, stream>>>(xf, bst1, xxb);
  for (int b0 = 0; b0 < NB; b0 += bpass) {
    pdgemmsym_kernel<3><<<dim3(NTRI, bpass), 256, 0, stream>>>(xf + b0 * bst1, bst1, xxb + b0 * NPTS, keys);
    select_kernel<<<512 * bpass, 256, 0, stream>>>(keys, idxb + (long)b0 * NPTS * KNN);
  }
  yzt_kernel<3><<<dim3(1, 32, NB), 256, 0, stream>>>(xf, bst1, W1f, 64, yb, zb);
  gmaxt_kernel<1><<<dim3(512, NB), 256, 0, stream>>>(yb, zb, idxb, g1f, b1f, cat, bstc, xxb);

  // ---- layer 2: C=64, O=64   (xx from gmaxt of layer 1)
  for (int b0 = 0; b0 < NB; b0 += bpass) {
    pdgemmsym_kernel<64><<<dim3(NTRI, bpass), 256, 0, stream>>>(cat + b0 * bstc, bstc, xxb + b0 * NPTS, keys);
    select_kernel<<<512 * bpass, 256, 0, stream>>>(keys, idxb + (long)b0 * NPTS * KNN);
  }
  yzt_kernel<64><<<dim3(1, 32, NB), 256, 0, stream>>>(cat, bstc, W2f, 64, yb, zb);
  gmaxt_kernel<1><<<dim3(512, NB), 256, 0, stream>>>(yb, zb, idxb, g2f, b2f_, cat + 64L * NPTS, bstc, xxb);

  // ---- layer 3: C=64, O=128
  for (int b0 = 0; b0 < NB; b0 += bpass) {
    pdgemmsym_kernel<64><<<dim3(NTRI, bpass), 256, 0, stream>>>(cat + 64L * NPTS + b0 * bstc, bstc, xxb + b0 * NPTS, keys);
    select_kernel<<<512 * bpass, 256, 0, stream>>>(keys, idxb + (long)b0 * NPTS * KNN);
  }
  yzt_kernel<64><<<dim3(2, 32, NB), 256, 0, stream>>>(cat + 64L * NPTS, bstc, W3f, 128, yb, zb);
  gmaxt_kernel<2><<<dim3(512, NB), 256, 0, stream>>>(yb, zb, idxb, g3f, b3f, cat + 128L * NPTS, bstc, xxb);

  // ---- layer 4: C=128, O=256
  for (int b0 = 0; b0 < NB; b0 += bpass) {
    pdgemmsym_kernel<128><<<dim3(NTRI, bpass), 256, 0, stream>>>(cat + 128L * NPTS + b0 * bstc, bstc, xxb + b0 * NPTS, keys);
    select_kernel<<<512 * bpass, 256, 0, stream>>>(keys, idxb + (long)b0 * NPTS * KNN);
  }
  yzt_kernel<128><<<dim3(4, 32, NB), 256, 0, stream>>>(cat + 128L * NPTS, bstc, W4f, 256, yb, zb);
  gmaxt_kernel<4><<<dim3(512, NB), 256, 0, stream>>>(yb, zb, idxb, g4f, b4f, cat + 256L * NPTS, bstc, (float*)nullptr);

  // ---- conv5 + BN + leaky + global max (128x128 tile)
  gemm5_kernel<<<dim3(16, 8, NB), 256, 0, stream>>>(cat, W5f, g5f, b5f, pmax);
  reduce5_kernel<<<16, 256, 0, stream>>>(pmax, vb);

  lfnf_kernel<<<NB, 128, 0, stream>>>(lf, nf, W6f, g6f, b6f, W7f, g7f, b7f, vb);

  head1_kernel<<<512, 256, 0, stream>>>(vb, L1f, g8f, b8f, v1b);
  head2_kernel<<<256, 256, 0, stream>>>(v1b, L2f, L2bf, g9f, b9f, v2b);
  head3_kernel<<<28, 256, 0, stream>>>(v2b, L3f, L3bf, d_out, flag);
}